// Round 1
// baseline (3890.834 us; speedup 1.0000x reference)
//
#include <hip/hip_runtime.h>

// Problem constants (from reference)
constexpr int NN = 100000;   // nodes
constexpr int D  = 128;      // feature dim (IN == HID)
constexpr int NE = 1000000;  // edges per layer
constexpr int NP = 100000;   // pos/neg pairs

// ---------------------------------------------------------------------------
// Scatter-add aggregation: agg[dst] += feat[src], deg[dst] += 1
// 32 threads per edge, each handling a float4 chunk of the 128-dim row.
// ---------------------------------------------------------------------------
__global__ void __launch_bounds__(256) scatter_kernel(
    const float* __restrict__ feat,
    const int* __restrict__ src,
    const int* __restrict__ dst,
    float* __restrict__ agg,
    float* __restrict__ deg,
    int nE)
{
    int tid = blockIdx.x * blockDim.x + threadIdx.x;
    int e = tid >> 5;
    if (e >= nE) return;
    int c = (tid & 31) << 2;
    int s = src[e], d = dst[e];
    float4 v = *reinterpret_cast<const float4*>(feat + (size_t)s * D + c);
    float* o = agg + (size_t)d * D + c;
    atomicAdd(o + 0, v.x);
    atomicAdd(o + 1, v.y);
    atomicAdd(o + 2, v.z);
    atomicAdd(o + 3, v.w);
    if ((tid & 31) == 0) atomicAdd(deg + d, 1.0f);
}

// ---------------------------------------------------------------------------
// Fused SAGEConv GEMM: out = act(X @ Wself + (AGG/deg') @ Wneigh + bias)
// Tile: 32 rows x 128 cols per block (256 threads), 4x4 register tile/thread,
// K chunked by 16 with weights staged in LDS. All LDS traffic is b128.
// ---------------------------------------------------------------------------
template<bool RELU>
__global__ void __launch_bounds__(256) sage_gemm_kernel(
    const float* __restrict__ X,
    const float* __restrict__ AGG,
    const float* __restrict__ deg,
    const float* __restrict__ Wself,
    const float* __restrict__ Wneigh,
    const float* __restrict__ bias,
    float* __restrict__ out,
    int nRows)
{
    __shared__ float xs[32][128];
    __shared__ float ms[32][128];
    __shared__ float ws_s[16][128];
    __shared__ float wn_s[16][128];

    int row0 = blockIdx.x * 32;
    int t = threadIdx.x;

    // Stage input tiles (x and mean = agg * 1/max(deg,1))
    for (int i = 0; i < 4; ++i) {
        int idx = t + i * 256;       // float4 slot 0..1023
        int r = idx >> 5;
        int c4 = (idx & 31) << 2;
        int gr = row0 + r;
        float4 xv = make_float4(0.f, 0.f, 0.f, 0.f);
        float4 av = xv;
        if (gr < nRows) {
            xv = *reinterpret_cast<const float4*>(X + (size_t)gr * D + c4);
            av = *reinterpret_cast<const float4*>(AGG + (size_t)gr * D + c4);
            float rd = 1.0f / fmaxf(deg[gr], 1.0f);
            av.x *= rd; av.y *= rd; av.z *= rd; av.w *= rd;
        }
        *reinterpret_cast<float4*>(&xs[r][c4]) = xv;
        *reinterpret_cast<float4*>(&ms[r][c4]) = av;
    }

    int tx = t & 31, ty = t >> 5;
    int c0 = tx << 2, r0 = ty << 2;
    float4 acc[4];
    for (int i = 0; i < 4; ++i) acc[i] = make_float4(0.f, 0.f, 0.f, 0.f);

    for (int kc = 0; kc < 8; ++kc) {
        __syncthreads();  // protect weight LDS reuse (also covers xs/ms on kc=0)
        for (int i = 0; i < 2; ++i) {
            int idx = t + i * 256;   // float4 slot 0..511
            int kk = idx >> 5;
            int c4 = (idx & 31) << 2;
            *reinterpret_cast<float4*>(&ws_s[kk][c4]) =
                *reinterpret_cast<const float4*>(Wself + (size_t)(kc * 16 + kk) * D + c4);
            *reinterpret_cast<float4*>(&wn_s[kk][c4]) =
                *reinterpret_cast<const float4*>(Wneigh + (size_t)(kc * 16 + kk) * D + c4);
        }
        __syncthreads();

        for (int k4 = 0; k4 < 4; ++k4) {
            int kb = kc * 16 + k4 * 4;   // global k base
            int lb = k4 * 4;             // local k base within chunk
            float4 xv[4], mv[4];
            for (int i = 0; i < 4; ++i) {
                xv[i] = *reinterpret_cast<const float4*>(&xs[r0 + i][kb]);
                mv[i] = *reinterpret_cast<const float4*>(&ms[r0 + i][kb]);
            }
            for (int j = 0; j < 4; ++j) {
                float4 wsv = *reinterpret_cast<const float4*>(&ws_s[lb + j][c0]);
                float4 wnv = *reinterpret_cast<const float4*>(&wn_s[lb + j][c0]);
                for (int i = 0; i < 4; ++i) {
                    float a = (&xv[i].x)[j];
                    float m = (&mv[i].x)[j];
                    acc[i].x += a * wsv.x + m * wnv.x;
                    acc[i].y += a * wsv.y + m * wnv.y;
                    acc[i].z += a * wsv.z + m * wnv.z;
                    acc[i].w += a * wsv.w + m * wnv.w;
                }
            }
        }
    }

    float4 bv = *reinterpret_cast<const float4*>(bias + c0);
    for (int i = 0; i < 4; ++i) {
        int gr = row0 + r0 + i;
        if (gr >= nRows) continue;
        float4 o;
        o.x = acc[i].x + bv.x;
        o.y = acc[i].y + bv.y;
        o.z = acc[i].z + bv.z;
        o.w = acc[i].w + bv.w;
        if (RELU) {
            o.x = fmaxf(o.x, 0.f); o.y = fmaxf(o.y, 0.f);
            o.z = fmaxf(o.z, 0.f); o.w = fmaxf(o.w, 0.f);
        }
        *reinterpret_cast<float4*>(out + (size_t)gr * D + c0) = o;
    }
}

// ---------------------------------------------------------------------------
// Predictor: out[p] = relu((h2[s]*h2[d]) @ Wp1 + bp1) @ Wp2 + bp2
// Same tile structure; final 128->1 GEMV fused via in-wave shuffle reduction.
// ---------------------------------------------------------------------------
__global__ void __launch_bounds__(256) predictor_kernel(
    const float* __restrict__ H,
    const int* __restrict__ srcI,
    const int* __restrict__ dstI,
    const float* __restrict__ Wp1,
    const float* __restrict__ bp1,
    const float* __restrict__ Wp2,
    const float* __restrict__ bp2,
    float* __restrict__ out,
    int nPairs)
{
    __shared__ float zs[32][128];
    __shared__ float wp_s[16][128];

    int row0 = blockIdx.x * 32;
    int t = threadIdx.x;

    for (int i = 0; i < 4; ++i) {
        int idx = t + i * 256;
        int r = idx >> 5;
        int c4 = (idx & 31) << 2;
        int p = row0 + r;
        float4 z = make_float4(0.f, 0.f, 0.f, 0.f);
        if (p < nPairs) {
            int s = srcI[p], d2 = dstI[p];
            float4 a = *reinterpret_cast<const float4*>(H + (size_t)s * D + c4);
            float4 b = *reinterpret_cast<const float4*>(H + (size_t)d2 * D + c4);
            z.x = a.x * b.x; z.y = a.y * b.y; z.z = a.z * b.z; z.w = a.w * b.w;
        }
        *reinterpret_cast<float4*>(&zs[r][c4]) = z;
    }

    int tx = t & 31, ty = t >> 5;
    int c0 = tx << 2, r0 = ty << 2;
    float4 acc[4];
    for (int i = 0; i < 4; ++i) acc[i] = make_float4(0.f, 0.f, 0.f, 0.f);

    for (int kc = 0; kc < 8; ++kc) {
        __syncthreads();
        for (int i = 0; i < 2; ++i) {
            int idx = t + i * 256;
            int kk = idx >> 5;
            int c4 = (idx & 31) << 2;
            *reinterpret_cast<float4*>(&wp_s[kk][c4]) =
                *reinterpret_cast<const float4*>(Wp1 + (size_t)(kc * 16 + kk) * D + c4);
        }
        __syncthreads();

        for (int k4 = 0; k4 < 4; ++k4) {
            int kb = kc * 16 + k4 * 4;
            int lb = k4 * 4;
            float4 zv[4];
            for (int i = 0; i < 4; ++i)
                zv[i] = *reinterpret_cast<const float4*>(&zs[r0 + i][kb]);
            for (int j = 0; j < 4; ++j) {
                float4 w = *reinterpret_cast<const float4*>(&wp_s[lb + j][c0]);
                for (int i = 0; i < 4; ++i) {
                    float zj = (&zv[i].x)[j];
                    acc[i].x += zj * w.x;
                    acc[i].y += zj * w.y;
                    acc[i].z += zj * w.z;
                    acc[i].w += zj * w.w;
                }
            }
        }
    }

    float4 bv = *reinterpret_cast<const float4*>(bp1 + c0);
    float4 w2 = *reinterpret_cast<const float4*>(Wp2 + c0);
    float b2s = bp2[0];
    for (int i = 0; i < 4; ++i) {
        float partial =
            fmaxf(acc[i].x + bv.x, 0.f) * w2.x +
            fmaxf(acc[i].y + bv.y, 0.f) * w2.y +
            fmaxf(acc[i].z + bv.z, 0.f) * w2.z +
            fmaxf(acc[i].w + bv.w, 0.f) * w2.w;
        // reduce across the 32 tx lanes (xor offsets < 32 stay in the ty group)
        for (int off = 16; off >= 1; off >>= 1)
            partial += __shfl_xor(partial, off);
        int p = row0 + r0 + i;
        if (tx == 0 && p < nPairs) out[p] = partial + b2s;
    }
}

// ---------------------------------------------------------------------------
extern "C" void kernel_launch(void* const* d_in, const int* in_sizes, int n_in,
                              void* d_out, int out_size, void* d_ws, size_t ws_size,
                              hipStream_t stream) {
    const float* x   = (const float*)d_in[0];
    const int*   es1 = (const int*)d_in[1];
    const int*   ed1 = (const int*)d_in[2];
    const int*   es2 = (const int*)d_in[3];
    const int*   ed2 = (const int*)d_in[4];
    const int*   ps  = (const int*)d_in[5];
    const int*   pd  = (const int*)d_in[6];
    const int*   ns  = (const int*)d_in[7];
    const int*   nd  = (const int*)d_in[8];
    const float* Ws1 = (const float*)d_in[9];
    const float* Wn1 = (const float*)d_in[10];
    const float* b1  = (const float*)d_in[11];
    const float* Ws2 = (const float*)d_in[12];
    const float* Wn2 = (const float*)d_in[13];
    const float* b2  = (const float*)d_in[14];
    const float* Wp1 = (const float*)d_in[15];
    const float* bp1 = (const float*)d_in[16];
    const float* Wp2 = (const float*)d_in[17];
    const float* bp2 = (const float*)d_in[18];
    float* out = (float*)d_out;

    char* ws = (char*)d_ws;
    size_t fbytes = (size_t)NN * D * sizeof(float);   // 51.2 MB
    float* agg = (float*)(ws);
    float* h   = (float*)(ws + fbytes);
    float* h2  = (float*)(ws + 2 * fbytes);
    float* deg = (float*)(ws + 3 * fbytes);

    dim3 blk(256);
    int scatterBlocks = (NE * 32 + 255) / 256;   // 125000
    int gemmBlocks = (NN + 31) / 32;             // 3125
    int predBlocks = (NP + 31) / 32;             // 3125

    // Layer 1
    hipMemsetAsync(agg, 0, fbytes, stream);
    hipMemsetAsync(deg, 0, NN * sizeof(float), stream);
    scatter_kernel<<<scatterBlocks, blk, 0, stream>>>(x, es1, ed1, agg, deg, NE);
    sage_gemm_kernel<true><<<gemmBlocks, blk, 0, stream>>>(x, agg, deg, Ws1, Wn1, b1, h, NN);

    // Layer 2
    hipMemsetAsync(agg, 0, fbytes, stream);
    hipMemsetAsync(deg, 0, NN * sizeof(float), stream);
    scatter_kernel<<<scatterBlocks, blk, 0, stream>>>(h, es2, ed2, agg, deg, NE);
    sage_gemm_kernel<false><<<gemmBlocks, blk, 0, stream>>>(h, agg, deg, Ws2, Wn2, b2, h2, NN);

    // Predictor (pos then neg, concatenated in d_out)
    predictor_kernel<<<predBlocks, blk, 0, stream>>>(h2, ps, pd, Wp1, bp1, Wp2, bp2, out, NP);
    predictor_kernel<<<predBlocks, blk, 0, stream>>>(h2, ns, nd, Wp1, bp1, Wp2, bp2, out + NP, NP);
}

// Round 2
// 1220.114 us; speedup vs baseline: 3.1889x; 3.1889x over previous
//
#include <hip/hip_runtime.h>

// Problem constants (from reference)
constexpr int NN = 100000;   // nodes
constexpr int D  = 128;      // feature dim (IN == HID)
constexpr int NE = 1000000;  // edges per layer
constexpr int NP = 100000;   // pos/neg pairs

// ---------------------------------------------------------------------------
// CSR build step 1: count in-degree per node
// ---------------------------------------------------------------------------
__global__ void __launch_bounds__(256) count_kernel(
    const int* __restrict__ dst, int* __restrict__ cnt, int nE)
{
    int e = blockIdx.x * blockDim.x + threadIdx.x;
    if (e >= nE) return;
    atomicAdd(&cnt[dst[e]], 1);
}

// ---------------------------------------------------------------------------
// CSR build step 2: exclusive prefix scan of cnt[NN] -> row_off[NN+1], cursor
// Single block of 1024 threads; each thread serial-scans a ~98-element chunk.
// ---------------------------------------------------------------------------
__global__ void __launch_bounds__(1024) scan_kernel(
    const int* __restrict__ cnt,
    int* __restrict__ row_off,
    int* __restrict__ cursor)
{
    __shared__ int sums[1024];
    int t = threadIdx.x;
    const int chunk = (NN + 1023) / 1024;
    int lo = t * chunk;
    int hi = min(lo + chunk, NN);
    int s = 0;
    for (int i = lo; i < hi; ++i) s += cnt[i];
    sums[t] = s;
    __syncthreads();
    for (int off = 1; off < 1024; off <<= 1) {
        int u = (t >= off) ? sums[t - off] : 0;
        __syncthreads();
        sums[t] += u;
        __syncthreads();
    }
    int base = sums[t] - s;   // exclusive prefix
    for (int i = lo; i < hi; ++i) {
        row_off[i] = base;
        cursor[i] = base;
        base += cnt[i];
    }
    if (lo < NN && hi == NN) row_off[NN] = base;
}

// ---------------------------------------------------------------------------
// CSR build step 3: fill adjacency (src indices grouped by dst)
// ---------------------------------------------------------------------------
__global__ void __launch_bounds__(256) fill_kernel(
    const int* __restrict__ src, const int* __restrict__ dst,
    int* __restrict__ cursor, int* __restrict__ csr, int nE)
{
    int e = blockIdx.x * blockDim.x + threadIdx.x;
    if (e >= nE) return;
    int pos = atomicAdd(&cursor[dst[e]], 1);
    csr[pos] = src[e];
}

// ---------------------------------------------------------------------------
// Gather-mean: 32 lanes per node; each lane owns a float4 column chunk.
// mean[n] = sum(feat[csr[j]]) / max(deg,1)
// ---------------------------------------------------------------------------
__global__ void __launch_bounds__(256) gather_mean_kernel(
    const float* __restrict__ feat,
    const int* __restrict__ row_off,
    const int* __restrict__ csr,
    float* __restrict__ mean,
    int nNodes)
{
    int tid = blockIdx.x * blockDim.x + threadIdx.x;
    int g = tid >> 5;
    if (g >= nNodes) return;
    int lane = tid & 31;
    int c = lane << 2;
    int beg = row_off[g], end = row_off[g + 1];
    float4 acc = make_float4(0.f, 0.f, 0.f, 0.f);
    for (int j = beg; j < end; ++j) {
        int s = csr[j];
        float4 v = *reinterpret_cast<const float4*>(feat + (size_t)s * D + c);
        acc.x += v.x; acc.y += v.y; acc.z += v.z; acc.w += v.w;
    }
    float rd = 1.0f / fmaxf((float)(end - beg), 1.0f);
    acc.x *= rd; acc.y *= rd; acc.z *= rd; acc.w *= rd;
    *reinterpret_cast<float4*>(mean + (size_t)g * D + c) = acc;
}

// ---------------------------------------------------------------------------
// Fused SAGEConv GEMM: out = act(X @ Wself + MEAN @ Wneigh + bias)
// Tile: 32 rows x 128 cols per block (256 threads), 4x4 register tile/thread,
// K chunked by 16 with weights staged in LDS. In-place out==MEAN is safe:
// each block reads its rows only during staging, writes them only at epilogue.
// ---------------------------------------------------------------------------
template<bool RELU>
__global__ void __launch_bounds__(256) sage_gemm_kernel(
    const float* __restrict__ X,
    const float* __restrict__ MEAN,
    const float* __restrict__ Wself,
    const float* __restrict__ Wneigh,
    const float* __restrict__ bias,
    float* __restrict__ out,
    int nRows)
{
    __shared__ float xs[32][128];
    __shared__ float ms[32][128];
    __shared__ float ws_s[16][128];
    __shared__ float wn_s[16][128];

    int row0 = blockIdx.x * 32;
    int t = threadIdx.x;

    for (int i = 0; i < 4; ++i) {
        int idx = t + i * 256;       // float4 slot 0..1023
        int r = idx >> 5;
        int c4 = (idx & 31) << 2;
        int gr = row0 + r;
        float4 xv = make_float4(0.f, 0.f, 0.f, 0.f);
        float4 av = xv;
        if (gr < nRows) {
            xv = *reinterpret_cast<const float4*>(X + (size_t)gr * D + c4);
            av = *reinterpret_cast<const float4*>(MEAN + (size_t)gr * D + c4);
        }
        *reinterpret_cast<float4*>(&xs[r][c4]) = xv;
        *reinterpret_cast<float4*>(&ms[r][c4]) = av;
    }

    int tx = t & 31, ty = t >> 5;
    int c0 = tx << 2, r0 = ty << 2;
    float4 acc[4];
    for (int i = 0; i < 4; ++i) acc[i] = make_float4(0.f, 0.f, 0.f, 0.f);

    for (int kc = 0; kc < 8; ++kc) {
        __syncthreads();
        for (int i = 0; i < 2; ++i) {
            int idx = t + i * 256;   // float4 slot 0..511
            int kk = idx >> 5;
            int c4 = (idx & 31) << 2;
            *reinterpret_cast<float4*>(&ws_s[kk][c4]) =
                *reinterpret_cast<const float4*>(Wself + (size_t)(kc * 16 + kk) * D + c4);
            *reinterpret_cast<float4*>(&wn_s[kk][c4]) =
                *reinterpret_cast<const float4*>(Wneigh + (size_t)(kc * 16 + kk) * D + c4);
        }
        __syncthreads();

        for (int k4 = 0; k4 < 4; ++k4) {
            int kb = kc * 16 + k4 * 4;
            int lb = k4 * 4;
            float4 xv[4], mv[4];
            for (int i = 0; i < 4; ++i) {
                xv[i] = *reinterpret_cast<const float4*>(&xs[r0 + i][kb]);
                mv[i] = *reinterpret_cast<const float4*>(&ms[r0 + i][kb]);
            }
            for (int j = 0; j < 4; ++j) {
                float4 wsv = *reinterpret_cast<const float4*>(&ws_s[lb + j][c0]);
                float4 wnv = *reinterpret_cast<const float4*>(&wn_s[lb + j][c0]);
                for (int i = 0; i < 4; ++i) {
                    float a = (&xv[i].x)[j];
                    float m = (&mv[i].x)[j];
                    acc[i].x += a * wsv.x + m * wnv.x;
                    acc[i].y += a * wsv.y + m * wnv.y;
                    acc[i].z += a * wsv.z + m * wnv.z;
                    acc[i].w += a * wsv.w + m * wnv.w;
                }
            }
        }
    }

    float4 bv = *reinterpret_cast<const float4*>(bias + c0);
    for (int i = 0; i < 4; ++i) {
        int gr = row0 + r0 + i;
        if (gr >= nRows) continue;
        float4 o;
        o.x = acc[i].x + bv.x;
        o.y = acc[i].y + bv.y;
        o.z = acc[i].z + bv.z;
        o.w = acc[i].w + bv.w;
        if (RELU) {
            o.x = fmaxf(o.x, 0.f); o.y = fmaxf(o.y, 0.f);
            o.z = fmaxf(o.z, 0.f); o.w = fmaxf(o.w, 0.f);
        }
        *reinterpret_cast<float4*>(out + (size_t)gr * D + c0) = o;
    }
}

// ---------------------------------------------------------------------------
// Predictor: out[p] = relu((h2[s]*h2[d]) @ Wp1 + bp1) @ Wp2 + bp2
// ---------------------------------------------------------------------------
__global__ void __launch_bounds__(256) predictor_kernel(
    const float* __restrict__ H,
    const int* __restrict__ srcI,
    const int* __restrict__ dstI,
    const float* __restrict__ Wp1,
    const float* __restrict__ bp1,
    const float* __restrict__ Wp2,
    const float* __restrict__ bp2,
    float* __restrict__ out,
    int nPairs)
{
    __shared__ float zs[32][128];
    __shared__ float wp_s[16][128];

    int row0 = blockIdx.x * 32;
    int t = threadIdx.x;

    for (int i = 0; i < 4; ++i) {
        int idx = t + i * 256;
        int r = idx >> 5;
        int c4 = (idx & 31) << 2;
        int p = row0 + r;
        float4 z = make_float4(0.f, 0.f, 0.f, 0.f);
        if (p < nPairs) {
            int s = srcI[p], d2 = dstI[p];
            float4 a = *reinterpret_cast<const float4*>(H + (size_t)s * D + c4);
            float4 b = *reinterpret_cast<const float4*>(H + (size_t)d2 * D + c4);
            z.x = a.x * b.x; z.y = a.y * b.y; z.z = a.z * b.z; z.w = a.w * b.w;
        }
        *reinterpret_cast<float4*>(&zs[r][c4]) = z;
    }

    int tx = t & 31, ty = t >> 5;
    int c0 = tx << 2, r0 = ty << 2;
    float4 acc[4];
    for (int i = 0; i < 4; ++i) acc[i] = make_float4(0.f, 0.f, 0.f, 0.f);

    for (int kc = 0; kc < 8; ++kc) {
        __syncthreads();
        for (int i = 0; i < 2; ++i) {
            int idx = t + i * 256;
            int kk = idx >> 5;
            int c4 = (idx & 31) << 2;
            *reinterpret_cast<float4*>(&wp_s[kk][c4]) =
                *reinterpret_cast<const float4*>(Wp1 + (size_t)(kc * 16 + kk) * D + c4);
        }
        __syncthreads();

        for (int k4 = 0; k4 < 4; ++k4) {
            int kb = kc * 16 + k4 * 4;
            int lb = k4 * 4;
            float4 zv[4];
            for (int i = 0; i < 4; ++i)
                zv[i] = *reinterpret_cast<const float4*>(&zs[r0 + i][kb]);
            for (int j = 0; j < 4; ++j) {
                float4 w = *reinterpret_cast<const float4*>(&wp_s[lb + j][c0]);
                for (int i = 0; i < 4; ++i) {
                    float zj = (&zv[i].x)[j];
                    acc[i].x += zj * w.x;
                    acc[i].y += zj * w.y;
                    acc[i].z += zj * w.z;
                    acc[i].w += zj * w.w;
                }
            }
        }
    }

    float4 bv = *reinterpret_cast<const float4*>(bp1 + c0);
    float4 w2 = *reinterpret_cast<const float4*>(Wp2 + c0);
    float b2s = bp2[0];
    for (int i = 0; i < 4; ++i) {
        float partial =
            fmaxf(acc[i].x + bv.x, 0.f) * w2.x +
            fmaxf(acc[i].y + bv.y, 0.f) * w2.y +
            fmaxf(acc[i].z + bv.z, 0.f) * w2.z +
            fmaxf(acc[i].w + bv.w, 0.f) * w2.w;
        for (int off = 16; off >= 1; off >>= 1)
            partial += __shfl_xor(partial, off);
        int p = row0 + r0 + i;
        if (tx == 0 && p < nPairs) out[p] = partial + b2s;
    }
}

// ---------------------------------------------------------------------------
extern "C" void kernel_launch(void* const* d_in, const int* in_sizes, int n_in,
                              void* d_out, int out_size, void* d_ws, size_t ws_size,
                              hipStream_t stream) {
    const float* x   = (const float*)d_in[0];
    const int*   es1 = (const int*)d_in[1];
    const int*   ed1 = (const int*)d_in[2];
    const int*   es2 = (const int*)d_in[3];
    const int*   ed2 = (const int*)d_in[4];
    const int*   ps  = (const int*)d_in[5];
    const int*   pd  = (const int*)d_in[6];
    const int*   ns  = (const int*)d_in[7];
    const int*   nd  = (const int*)d_in[8];
    const float* Ws1 = (const float*)d_in[9];
    const float* Wn1 = (const float*)d_in[10];
    const float* b1  = (const float*)d_in[11];
    const float* Ws2 = (const float*)d_in[12];
    const float* Wn2 = (const float*)d_in[13];
    const float* b2  = (const float*)d_in[14];
    const float* Wp1 = (const float*)d_in[15];
    const float* bp1 = (const float*)d_in[16];
    const float* Wp2 = (const float*)d_in[17];
    const float* bp2 = (const float*)d_in[18];
    float* out = (float*)d_out;

    char* ws = (char*)d_ws;
    size_t fbytes = (size_t)NN * D * sizeof(float);   // 51.2 MB
    float* mean = (float*)(ws);                        // also h2 (in-place)
    float* h    = (float*)(ws + fbytes);
    int* cnt     = (int*)(ws + 2 * fbytes);
    int* row_off = cnt + NN;            // NN+1
    int* cursor  = row_off + NN + 1;    // NN
    int* csr     = cursor + NN;         // NE
    float* h2 = mean;

    dim3 blk(256);
    int edgeBlocks   = (NE + 255) / 256;         // 3907
    int gatherBlocks = (NN * 32 + 255) / 256;    // 12500
    int gemmBlocks   = (NN + 31) / 32;           // 3125
    int predBlocks   = (NP + 31) / 32;           // 3125

    // ---- Layer 1 ----
    hipMemsetAsync(cnt, 0, NN * sizeof(int), stream);
    count_kernel<<<edgeBlocks, blk, 0, stream>>>(ed1, cnt, NE);
    scan_kernel<<<1, 1024, 0, stream>>>(cnt, row_off, cursor);
    fill_kernel<<<edgeBlocks, blk, 0, stream>>>(es1, ed1, cursor, csr, NE);
    gather_mean_kernel<<<gatherBlocks, blk, 0, stream>>>(x, row_off, csr, mean, NN);
    sage_gemm_kernel<true><<<gemmBlocks, blk, 0, stream>>>(x, mean, Ws1, Wn1, b1, h, NN);

    // ---- Layer 2 ----
    hipMemsetAsync(cnt, 0, NN * sizeof(int), stream);
    count_kernel<<<edgeBlocks, blk, 0, stream>>>(ed2, cnt, NE);
    scan_kernel<<<1, 1024, 0, stream>>>(cnt, row_off, cursor);
    fill_kernel<<<edgeBlocks, blk, 0, stream>>>(es2, ed2, cursor, csr, NE);
    gather_mean_kernel<<<gatherBlocks, blk, 0, stream>>>(h, row_off, csr, mean, NN);
    sage_gemm_kernel<false><<<gemmBlocks, blk, 0, stream>>>(h, mean, Ws2, Wn2, b2, h2, NN);

    // ---- Predictor ----
    predictor_kernel<<<predBlocks, blk, 0, stream>>>(h2, ps, pd, Wp1, bp1, Wp2, bp2, out, NP);
    predictor_kernel<<<predBlocks, blk, 0, stream>>>(h2, ns, nd, Wp1, bp1, Wp2, bp2, out + NP, NP);
}

// Round 3
// 782.351 us; speedup vs baseline: 4.9733x; 1.5595x over previous
//
#include <hip/hip_runtime.h>

// Problem constants (from reference)
constexpr int NN = 100000;   // nodes
constexpr int D  = 128;      // feature dim (IN == HID)
constexpr int NE = 1000000;  // edges per layer
constexpr int NP = 100000;   // pos/neg pairs
constexpr int NB = (NN + 255) / 256;   // 391 scan blocks

// ---------------------------------------------------------------------------
// CSR build step 1: count in-degree per node
// ---------------------------------------------------------------------------
__global__ void __launch_bounds__(256) count_kernel(
    const int* __restrict__ dst, int* __restrict__ cnt, int nE)
{
    int e = blockIdx.x * blockDim.x + threadIdx.x;
    if (e >= nE) return;
    atomicAdd(&cnt[dst[e]], 1);
}

// ---------------------------------------------------------------------------
// CSR build step 2a: per-block sums of cnt
// ---------------------------------------------------------------------------
__global__ void __launch_bounds__(256) block_sum_kernel(
    const int* __restrict__ cnt, int* __restrict__ bsums)
{
    __shared__ int red[4];
    int i = blockIdx.x * 256 + threadIdx.x;
    int v = (i < NN) ? cnt[i] : 0;
    for (int off = 32; off >= 1; off >>= 1) v += __shfl_xor(v, off);
    int wave = threadIdx.x >> 6;
    if ((threadIdx.x & 63) == 0) red[wave] = v;
    __syncthreads();
    if (threadIdx.x == 0)
        bsums[blockIdx.x] = red[0] + red[1] + red[2] + red[3];
}

// ---------------------------------------------------------------------------
// CSR build step 2b: exclusive scan of the NB block sums (single block)
// ---------------------------------------------------------------------------
__global__ void __launch_bounds__(512) scan_sums_kernel(int* __restrict__ bsums)
{
    __shared__ int s[512];
    int t = threadIdx.x;
    int v = (t < NB) ? bsums[t] : 0;
    s[t] = v;
    __syncthreads();
    for (int off = 1; off < 512; off <<= 1) {
        int u = (t >= off) ? s[t - off] : 0;
        __syncthreads();
        s[t] += u;
        __syncthreads();
    }
    if (t < NB) bsums[t] = s[t] - v;   // exclusive prefix
}

// ---------------------------------------------------------------------------
// CSR build step 2c: per-block scan + base -> row_off, cursor
// ---------------------------------------------------------------------------
__global__ void __launch_bounds__(256) block_scan_kernel(
    const int* __restrict__ cnt, const int* __restrict__ bsums,
    int* __restrict__ row_off, int* __restrict__ cursor)
{
    __shared__ int s[256];
    int t = threadIdx.x;
    int i = blockIdx.x * 256 + t;
    int v = (i < NN) ? cnt[i] : 0;
    s[t] = v;
    __syncthreads();
    for (int off = 1; off < 256; off <<= 1) {
        int u = (t >= off) ? s[t - off] : 0;
        __syncthreads();
        s[t] += u;
        __syncthreads();
    }
    int ex = s[t] - v + bsums[blockIdx.x];
    if (i < NN) { row_off[i] = ex; cursor[i] = ex; }
    if (i == 0) row_off[NN] = NE;   // all dst in [0,NN) -> total is exactly NE
}

// ---------------------------------------------------------------------------
// CSR build step 3: fill adjacency (src indices grouped by dst)
// ---------------------------------------------------------------------------
__global__ void __launch_bounds__(256) fill_kernel(
    const int* __restrict__ src, const int* __restrict__ dst,
    int* __restrict__ cursor, int* __restrict__ csr, int nE)
{
    int e = blockIdx.x * blockDim.x + threadIdx.x;
    if (e >= nE) return;
    int pos = atomicAdd(&cursor[dst[e]], 1);
    csr[pos] = src[e];
}

// ---------------------------------------------------------------------------
// Gather-mean: 32 lanes per node; each lane owns a float4 column chunk.
// ---------------------------------------------------------------------------
__global__ void __launch_bounds__(256) gather_mean_kernel(
    const float* __restrict__ feat,
    const int* __restrict__ row_off,
    const int* __restrict__ csr,
    float* __restrict__ mean,
    int nNodes)
{
    int tid = blockIdx.x * blockDim.x + threadIdx.x;
    int g = tid >> 5;
    if (g >= nNodes) return;
    int lane = tid & 31;
    int c = lane << 2;
    int beg = row_off[g], end = row_off[g + 1];
    float4 acc = make_float4(0.f, 0.f, 0.f, 0.f);
    for (int j = beg; j < end; ++j) {
        int s = csr[j];
        float4 v = *reinterpret_cast<const float4*>(feat + (size_t)s * D + c);
        acc.x += v.x; acc.y += v.y; acc.z += v.z; acc.w += v.w;
    }
    float rd = 1.0f / fmaxf((float)(end - beg), 1.0f);
    acc.x *= rd; acc.y *= rd; acc.z *= rd; acc.w *= rd;
    *reinterpret_cast<float4*>(mean + (size_t)g * D + c) = acc;
}

// ---------------------------------------------------------------------------
// Fused SAGEConv GEMM: out = act(X @ Wself + MEAN @ Wneigh + bias)
// In-place out==MEAN is safe (reads at staging, writes at epilogue only).
// ---------------------------------------------------------------------------
template<bool RELU>
__global__ void __launch_bounds__(256) sage_gemm_kernel(
    const float* __restrict__ X,
    const float* __restrict__ MEAN,
    const float* __restrict__ Wself,
    const float* __restrict__ Wneigh,
    const float* __restrict__ bias,
    float* __restrict__ out,
    int nRows)
{
    __shared__ float xs[32][128];
    __shared__ float ms[32][128];
    __shared__ float ws_s[16][128];
    __shared__ float wn_s[16][128];

    int row0 = blockIdx.x * 32;
    int t = threadIdx.x;

    for (int i = 0; i < 4; ++i) {
        int idx = t + i * 256;
        int r = idx >> 5;
        int c4 = (idx & 31) << 2;
        int gr = row0 + r;
        float4 xv = make_float4(0.f, 0.f, 0.f, 0.f);
        float4 av = xv;
        if (gr < nRows) {
            xv = *reinterpret_cast<const float4*>(X + (size_t)gr * D + c4);
            av = *reinterpret_cast<const float4*>(MEAN + (size_t)gr * D + c4);
        }
        *reinterpret_cast<float4*>(&xs[r][c4]) = xv;
        *reinterpret_cast<float4*>(&ms[r][c4]) = av;
    }

    int tx = t & 31, ty = t >> 5;
    int c0 = tx << 2, r0 = ty << 2;
    float4 acc[4];
    for (int i = 0; i < 4; ++i) acc[i] = make_float4(0.f, 0.f, 0.f, 0.f);

    for (int kc = 0; kc < 8; ++kc) {
        __syncthreads();
        for (int i = 0; i < 2; ++i) {
            int idx = t + i * 256;
            int kk = idx >> 5;
            int c4 = (idx & 31) << 2;
            *reinterpret_cast<float4*>(&ws_s[kk][c4]) =
                *reinterpret_cast<const float4*>(Wself + (size_t)(kc * 16 + kk) * D + c4);
            *reinterpret_cast<float4*>(&wn_s[kk][c4]) =
                *reinterpret_cast<const float4*>(Wneigh + (size_t)(kc * 16 + kk) * D + c4);
        }
        __syncthreads();

        for (int k4 = 0; k4 < 4; ++k4) {
            int kb = kc * 16 + k4 * 4;
            int lb = k4 * 4;
            float4 xv[4], mv[4];
            for (int i = 0; i < 4; ++i) {
                xv[i] = *reinterpret_cast<const float4*>(&xs[r0 + i][kb]);
                mv[i] = *reinterpret_cast<const float4*>(&ms[r0 + i][kb]);
            }
            for (int j = 0; j < 4; ++j) {
                float4 wsv = *reinterpret_cast<const float4*>(&ws_s[lb + j][c0]);
                float4 wnv = *reinterpret_cast<const float4*>(&wn_s[lb + j][c0]);
                for (int i = 0; i < 4; ++i) {
                    float a = (&xv[i].x)[j];
                    float m = (&mv[i].x)[j];
                    acc[i].x += a * wsv.x + m * wnv.x;
                    acc[i].y += a * wsv.y + m * wnv.y;
                    acc[i].z += a * wsv.z + m * wnv.z;
                    acc[i].w += a * wsv.w + m * wnv.w;
                }
            }
        }
    }

    float4 bv = *reinterpret_cast<const float4*>(bias + c0);
    for (int i = 0; i < 4; ++i) {
        int gr = row0 + r0 + i;
        if (gr >= nRows) continue;
        float4 o;
        o.x = acc[i].x + bv.x;
        o.y = acc[i].y + bv.y;
        o.z = acc[i].z + bv.z;
        o.w = acc[i].w + bv.w;
        if (RELU) {
            o.x = fmaxf(o.x, 0.f); o.y = fmaxf(o.y, 0.f);
            o.z = fmaxf(o.z, 0.f); o.w = fmaxf(o.w, 0.f);
        }
        *reinterpret_cast<float4*>(out + (size_t)gr * D + c0) = o;
    }
}

// ---------------------------------------------------------------------------
// Predictor: out[p] = relu((h2[s]*h2[d]) @ Wp1 + bp1) @ Wp2 + bp2
// ---------------------------------------------------------------------------
__global__ void __launch_bounds__(256) predictor_kernel(
    const float* __restrict__ H,
    const int* __restrict__ srcI,
    const int* __restrict__ dstI,
    const float* __restrict__ Wp1,
    const float* __restrict__ bp1,
    const float* __restrict__ Wp2,
    const float* __restrict__ bp2,
    float* __restrict__ out,
    int nPairs)
{
    __shared__ float zs[32][128];
    __shared__ float wp_s[16][128];

    int row0 = blockIdx.x * 32;
    int t = threadIdx.x;

    for (int i = 0; i < 4; ++i) {
        int idx = t + i * 256;
        int r = idx >> 5;
        int c4 = (idx & 31) << 2;
        int p = row0 + r;
        float4 z = make_float4(0.f, 0.f, 0.f, 0.f);
        if (p < nPairs) {
            int s = srcI[p], d2 = dstI[p];
            float4 a = *reinterpret_cast<const float4*>(H + (size_t)s * D + c4);
            float4 b = *reinterpret_cast<const float4*>(H + (size_t)d2 * D + c4);
            z.x = a.x * b.x; z.y = a.y * b.y; z.z = a.z * b.z; z.w = a.w * b.w;
        }
        *reinterpret_cast<float4*>(&zs[r][c4]) = z;
    }

    int tx = t & 31, ty = t >> 5;
    int c0 = tx << 2, r0 = ty << 2;
    float4 acc[4];
    for (int i = 0; i < 4; ++i) acc[i] = make_float4(0.f, 0.f, 0.f, 0.f);

    for (int kc = 0; kc < 8; ++kc) {
        __syncthreads();
        for (int i = 0; i < 2; ++i) {
            int idx = t + i * 256;
            int kk = idx >> 5;
            int c4 = (idx & 31) << 2;
            *reinterpret_cast<float4*>(&wp_s[kk][c4]) =
                *reinterpret_cast<const float4*>(Wp1 + (size_t)(kc * 16 + kk) * D + c4);
        }
        __syncthreads();

        for (int k4 = 0; k4 < 4; ++k4) {
            int kb = kc * 16 + k4 * 4;
            int lb = k4 * 4;
            float4 zv[4];
            for (int i = 0; i < 4; ++i)
                zv[i] = *reinterpret_cast<const float4*>(&zs[r0 + i][kb]);
            for (int j = 0; j < 4; ++j) {
                float4 w = *reinterpret_cast<const float4*>(&wp_s[lb + j][c0]);
                for (int i = 0; i < 4; ++i) {
                    float zj = (&zv[i].x)[j];
                    acc[i].x += zj * w.x;
                    acc[i].y += zj * w.y;
                    acc[i].z += zj * w.z;
                    acc[i].w += zj * w.w;
                }
            }
        }
    }

    float4 bv = *reinterpret_cast<const float4*>(bp1 + c0);
    float4 w2 = *reinterpret_cast<const float4*>(Wp2 + c0);
    float b2s = bp2[0];
    for (int i = 0; i < 4; ++i) {
        float partial =
            fmaxf(acc[i].x + bv.x, 0.f) * w2.x +
            fmaxf(acc[i].y + bv.y, 0.f) * w2.y +
            fmaxf(acc[i].z + bv.z, 0.f) * w2.z +
            fmaxf(acc[i].w + bv.w, 0.f) * w2.w;
        for (int off = 16; off >= 1; off >>= 1)
            partial += __shfl_xor(partial, off);
        int p = row0 + r0 + i;
        if (tx == 0 && p < nPairs) out[p] = partial + b2s;
    }
}

// ---------------------------------------------------------------------------
extern "C" void kernel_launch(void* const* d_in, const int* in_sizes, int n_in,
                              void* d_out, int out_size, void* d_ws, size_t ws_size,
                              hipStream_t stream) {
    const float* x   = (const float*)d_in[0];
    const int*   es1 = (const int*)d_in[1];
    const int*   ed1 = (const int*)d_in[2];
    const int*   es2 = (const int*)d_in[3];
    const int*   ed2 = (const int*)d_in[4];
    const int*   ps  = (const int*)d_in[5];
    const int*   pd  = (const int*)d_in[6];
    const int*   ns  = (const int*)d_in[7];
    const int*   nd  = (const int*)d_in[8];
    const float* Ws1 = (const float*)d_in[9];
    const float* Wn1 = (const float*)d_in[10];
    const float* b1  = (const float*)d_in[11];
    const float* Ws2 = (const float*)d_in[12];
    const float* Wn2 = (const float*)d_in[13];
    const float* b2  = (const float*)d_in[14];
    const float* Wp1 = (const float*)d_in[15];
    const float* bp1 = (const float*)d_in[16];
    const float* Wp2 = (const float*)d_in[17];
    const float* bp2 = (const float*)d_in[18];
    float* out = (float*)d_out;

    char* ws = (char*)d_ws;
    size_t fbytes = (size_t)NN * D * sizeof(float);   // 51.2 MB
    float* mean = (float*)(ws);                        // also h2 (in-place)
    float* h    = (float*)(ws + fbytes);
    int* cnt     = (int*)(ws + 2 * fbytes);
    int* row_off = cnt + NN;            // NN+1
    int* cursor  = row_off + NN + 1;    // NN
    int* csr     = cursor + NN;         // NE
    int* bsums   = csr + NE;            // NB
    float* h2 = mean;

    dim3 blk(256);
    int edgeBlocks   = (NE + 255) / 256;         // 3907
    int gatherBlocks = (NN * 32 + 255) / 256;    // 12500
    int gemmBlocks   = (NN + 31) / 32;           // 3125
    int predBlocks   = (NP + 31) / 32;           // 3125

    // ---- Layer 1 ----
    hipMemsetAsync(cnt, 0, NN * sizeof(int), stream);
    count_kernel<<<edgeBlocks, blk, 0, stream>>>(ed1, cnt, NE);
    block_sum_kernel<<<NB, blk, 0, stream>>>(cnt, bsums);
    scan_sums_kernel<<<1, 512, 0, stream>>>(bsums);
    block_scan_kernel<<<NB, blk, 0, stream>>>(cnt, bsums, row_off, cursor);
    fill_kernel<<<edgeBlocks, blk, 0, stream>>>(es1, ed1, cursor, csr, NE);
    gather_mean_kernel<<<gatherBlocks, blk, 0, stream>>>(x, row_off, csr, mean, NN);
    sage_gemm_kernel<true><<<gemmBlocks, blk, 0, stream>>>(x, mean, Ws1, Wn1, b1, h, NN);

    // ---- Layer 2 ----
    hipMemsetAsync(cnt, 0, NN * sizeof(int), stream);
    count_kernel<<<edgeBlocks, blk, 0, stream>>>(ed2, cnt, NE);
    block_sum_kernel<<<NB, blk, 0, stream>>>(cnt, bsums);
    scan_sums_kernel<<<1, 512, 0, stream>>>(bsums);
    block_scan_kernel<<<NB, blk, 0, stream>>>(cnt, bsums, row_off, cursor);
    fill_kernel<<<edgeBlocks, blk, 0, stream>>>(es2, ed2, cursor, csr, NE);
    gather_mean_kernel<<<gatherBlocks, blk, 0, stream>>>(h, row_off, csr, mean, NN);
    sage_gemm_kernel<false><<<gemmBlocks, blk, 0, stream>>>(h, mean, Ws2, Wn2, b2, h2, NN);

    // ---- Predictor ----
    predictor_kernel<<<predBlocks, blk, 0, stream>>>(h2, ps, pd, Wp1, bp1, Wp2, bp2, out, NP);
    predictor_kernel<<<predBlocks, blk, 0, stream>>>(h2, ns, nd, Wp1, bp1, Wp2, bp2, out + NP, NP);
}

// Round 4
// 560.267 us; speedup vs baseline: 6.9446x; 1.3964x over previous
//
#include <hip/hip_runtime.h>

typedef unsigned short ushort_t;
typedef __attribute__((ext_vector_type(8))) short short8;
typedef __attribute__((ext_vector_type(4))) float f32x4;

// Problem constants
constexpr int NN = 100000;   // nodes
constexpr int D  = 128;      // feature dim
constexpr int NE = 1000000;  // edges per layer
constexpr int NP = 100000;   // pos/neg pairs
constexpr int NB = (NN + 255) / 256;   // scan blocks

// ---------------- bf16 helpers (manual RNE, no __bf16 dependency) ----------
__device__ __forceinline__ float bf2f(ushort_t u) {
    union { unsigned int i; float f; } v; v.i = ((unsigned int)u) << 16; return v.f;
}
__device__ __forceinline__ ushort_t f2bf(float x) {
    union { float f; unsigned int i; } v; v.f = x;
    unsigned int r = v.i + 0x7fffu + ((v.i >> 16) & 1u);
    return (ushort_t)(r >> 16);
}
__device__ __forceinline__ void split2(float x, ushort_t& h, ushort_t& l) {
    h = f2bf(x);
    l = f2bf(x - bf2f(h));
}

// ---------------------------------------------------------------------------
// Prep: split x into hi/lo bf16 arrays [NN][128]
// ---------------------------------------------------------------------------
__global__ void __launch_bounds__(256) convert_x_kernel(
    const float* __restrict__ x, ushort_t* __restrict__ xh, ushort_t* __restrict__ xl)
{
    int tid = blockIdx.x * 256 + threadIdx.x;     // NN*32 threads, 4 elems each
    float4 v = *reinterpret_cast<const float4*>(x + (size_t)tid * 4);
    ushort4 h4, l4;
    split2(v.x, h4.x, l4.x); split2(v.y, h4.y, l4.y);
    split2(v.z, h4.z, l4.z); split2(v.w, h4.w, l4.w);
    *reinterpret_cast<ushort4*>(xh + (size_t)tid * 4) = h4;
    *reinterpret_cast<ushort4*>(xl + (size_t)tid * 4) = l4;
}

// ---------------------------------------------------------------------------
// Prep: W = [Wself; Wneigh] (256k x 128n) -> transposed hi/lo [128n][256k]
// ---------------------------------------------------------------------------
__global__ void __launch_bounds__(256) prep_wt_kernel(
    const float* __restrict__ Ws, const float* __restrict__ Wn,
    ushort_t* __restrict__ Wth, ushort_t* __restrict__ Wtl)
{
    int tid = blockIdx.x * 256 + threadIdx.x;   // 32768 threads
    int k = tid >> 7, n = tid & 127;
    float v = (k < 128) ? Ws[k * 128 + n] : Wn[(k - 128) * 128 + n];
    ushort_t h, l; split2(v, h, l);
    Wth[n * 256 + k] = h; Wtl[n * 256 + k] = l;
}

// Wp1 (128x128) -> transposed hi/lo [128n][128k]
__global__ void __launch_bounds__(256) prep_wp_kernel(
    const float* __restrict__ Wp1, ushort_t* __restrict__ Wth, ushort_t* __restrict__ Wtl)
{
    int tid = blockIdx.x * 256 + threadIdx.x;   // 16384 threads
    int k = tid >> 7, n = tid & 127;
    float v = Wp1[k * 128 + n];
    ushort_t h, l; split2(v, h, l);
    Wth[n * 128 + k] = h; Wtl[n * 128 + k] = l;
}

// ---------------------------------------------------------------------------
// CSR build
// ---------------------------------------------------------------------------
__global__ void __launch_bounds__(256) count_kernel(
    const int* __restrict__ dst, int* __restrict__ cnt, int nE)
{
    int e = blockIdx.x * blockDim.x + threadIdx.x;
    if (e >= nE) return;
    atomicAdd(&cnt[dst[e]], 1);
}

__global__ void __launch_bounds__(256) block_sum_kernel(
    const int* __restrict__ cnt, int* __restrict__ bsums)
{
    __shared__ int red[4];
    int i = blockIdx.x * 256 + threadIdx.x;
    int v = (i < NN) ? cnt[i] : 0;
    for (int off = 32; off >= 1; off >>= 1) v += __shfl_xor(v, off);
    int wave = threadIdx.x >> 6;
    if ((threadIdx.x & 63) == 0) red[wave] = v;
    __syncthreads();
    if (threadIdx.x == 0)
        bsums[blockIdx.x] = red[0] + red[1] + red[2] + red[3];
}

__global__ void __launch_bounds__(512) scan_sums_kernel(int* __restrict__ bsums)
{
    __shared__ int s[512];
    int t = threadIdx.x;
    int v = (t < NB) ? bsums[t] : 0;
    s[t] = v;
    __syncthreads();
    for (int off = 1; off < 512; off <<= 1) {
        int u = (t >= off) ? s[t - off] : 0;
        __syncthreads();
        s[t] += u;
        __syncthreads();
    }
    if (t < NB) bsums[t] = s[t] - v;
}

__global__ void __launch_bounds__(256) block_scan_kernel(
    const int* __restrict__ cnt, const int* __restrict__ bsums,
    int* __restrict__ row_off, int* __restrict__ cursor)
{
    __shared__ int s[256];
    int t = threadIdx.x;
    int i = blockIdx.x * 256 + t;
    int v = (i < NN) ? cnt[i] : 0;
    s[t] = v;
    __syncthreads();
    for (int off = 1; off < 256; off <<= 1) {
        int u = (t >= off) ? s[t - off] : 0;
        __syncthreads();
        s[t] += u;
        __syncthreads();
    }
    int ex = s[t] - v + bsums[blockIdx.x];
    if (i < NN) { row_off[i] = ex; cursor[i] = ex; }
    if (i == 0) row_off[NN] = NE;
}

__global__ void __launch_bounds__(256) fill_kernel(
    const int* __restrict__ src, const int* __restrict__ dst,
    int* __restrict__ cursor, int* __restrict__ csr, int nE)
{
    int e = blockIdx.x * blockDim.x + threadIdx.x;
    if (e >= nE) return;
    int pos = atomicAdd(&cursor[dst[e]], 1);
    csr[pos] = src[e];
}

// ---------------------------------------------------------------------------
// Gather-mean on hi/lo bf16 features -> hi/lo bf16 mean
// ---------------------------------------------------------------------------
__global__ void __launch_bounds__(256) gather_mean_kernel(
    const ushort_t* __restrict__ fh, const ushort_t* __restrict__ fl,
    const int* __restrict__ row_off, const int* __restrict__ csr,
    ushort_t* __restrict__ mh, ushort_t* __restrict__ ml)
{
    int tid = blockIdx.x * 256 + threadIdx.x;
    int g = tid >> 5;
    int lane = tid & 31;
    int c = lane << 2;
    int beg = row_off[g], end = row_off[g + 1];
    float ax = 0.f, ay = 0.f, az = 0.f, aw = 0.f;
    for (int j = beg; j < end; ++j) {
        int s = csr[j];
        ushort4 vh = *reinterpret_cast<const ushort4*>(fh + (size_t)s * D + c);
        ushort4 vl = *reinterpret_cast<const ushort4*>(fl + (size_t)s * D + c);
        ax += bf2f(vh.x) + bf2f(vl.x);
        ay += bf2f(vh.y) + bf2f(vl.y);
        az += bf2f(vh.z) + bf2f(vl.z);
        aw += bf2f(vh.w) + bf2f(vl.w);
    }
    float rd = 1.0f / fmaxf((float)(end - beg), 1.0f);
    ax *= rd; ay *= rd; az *= rd; aw *= rd;
    ushort4 h4, l4;
    split2(ax, h4.x, l4.x); split2(ay, h4.y, l4.y);
    split2(az, h4.z, l4.z); split2(aw, h4.w, l4.w);
    *reinterpret_cast<ushort4*>(mh + (size_t)g * D + c) = h4;
    *reinterpret_cast<ushort4*>(ml + (size_t)g * D + c) = l4;
}

// ---------------------------------------------------------------------------
// MFMA split-bf16 SAGEConv GEMM.
// out = act([A_self | A_neigh](N x 256) @ Wt^T + b), A given as hi/lo bf16.
// Block: 32 rows x 128 cols, 4 waves = 2 row-tiles x 2 col-halves.
// A fragments straight from global; B (transposed weights) staged in LDS
// per 64-k chunk with XOR swizzle ((n&7)<<4) for conflict-free ds_read_b128.
// 3-product split: Ah*Bh + Ah*Bl + Al*Bh. Emits hi/lo bf16 output.
// ---------------------------------------------------------------------------
template<bool RELU>
__global__ void __launch_bounds__(256) mfma_sage_gemm(
    const ushort_t* __restrict__ Ah_self, const ushort_t* __restrict__ Al_self,
    const ushort_t* __restrict__ Ah_nei,  const ushort_t* __restrict__ Al_nei,
    const ushort_t* __restrict__ Wth, const ushort_t* __restrict__ Wtl,
    const float* __restrict__ bias,
    ushort_t* __restrict__ out_h, ushort_t* __restrict__ out_l)
{
    __shared__ short Bh[128 * 64];   // [n][64k] bf16, swizzled
    __shared__ short Bl[128 * 64];

    int t = threadIdx.x;
    int l = t & 63, w = t >> 6;
    int rt = w >> 1, ch = w & 1;
    int lrow = l & 15, kg = l >> 4;
    int row0 = blockIdx.x * 32;            // grid is exact (100000/32 = 3125)
    int arow = row0 + rt * 16 + lrow;

    f32x4 acc[4];
    for (int i = 0; i < 4; ++i) acc[i] = (f32x4)(0.f);

    for (int half = 0; half < 2; ++half) {
        const ushort_t* Ah = half ? Ah_nei : Ah_self;
        const ushort_t* Al = half ? Al_nei : Al_self;
        for (int kc2 = 0; kc2 < 2; ++kc2) {
            int kcat = half * 128 + kc2 * 64;   // position in concatenated K=256
            __syncthreads();
            // stage B chunk: Wt[n][kcat..kcat+64] hi+lo, swizzled
            for (int i = 0; i < 4; ++i) {
                int s = t + i * 256;            // 1024 b128 slots
                int n = s >> 3;
                int k8 = (s & 7) * 8;
                short8 vh = *reinterpret_cast<const short8*>(Wth + n * 256 + kcat + k8);
                short8 vl = *reinterpret_cast<const short8*>(Wtl + n * 256 + kcat + k8);
                int db = n * 128 + ((k8 * 2) ^ ((n & 7) << 4));
                *reinterpret_cast<short8*>((char*)Bh + db) = vh;
                *reinterpret_cast<short8*>((char*)Bl + db) = vl;
            }
            __syncthreads();

            for (int ks = 0; ks < 2; ++ks) {
                int ka = kc2 * 64 + ks * 32 + kg * 8;   // k within this half's A
                short8 ah = *reinterpret_cast<const short8*>(Ah + (size_t)arow * D + ka);
                short8 al = *reinterpret_cast<const short8*>(Al + (size_t)arow * D + ka);
                int kb2 = (ks * 32 + kg * 8) * 2;
                for (int ct = 0; ct < 4; ++ct) {
                    int n = ch * 64 + ct * 16 + lrow;
                    int db = n * 128 + (kb2 ^ ((n & 7) << 4));
                    short8 bh = *reinterpret_cast<const short8*>((char*)Bh + db);
                    short8 bl = *reinterpret_cast<const short8*>((char*)Bl + db);
                    acc[ct] = __builtin_amdgcn_mfma_f32_16x16x32_bf16(ah, bh, acc[ct], 0, 0, 0);
                    acc[ct] = __builtin_amdgcn_mfma_f32_16x16x32_bf16(ah, bl, acc[ct], 0, 0, 0);
                    acc[ct] = __builtin_amdgcn_mfma_f32_16x16x32_bf16(al, bh, acc[ct], 0, 0, 0);
                }
            }
        }
    }

    // epilogue: C/D layout col = lane&15, row = (lane>>4)*4 + j
    for (int ct = 0; ct < 4; ++ct) {
        int n = ch * 64 + ct * 16 + lrow;
        float bv = bias[n];
        for (int j = 0; j < 4; ++j) {
            int r = row0 + rt * 16 + kg * 4 + j;
            float y = acc[ct][j] + bv;
            if (RELU) y = fmaxf(y, 0.f);
            ushort_t hh, ll; split2(y, hh, ll);
            out_h[(size_t)r * D + n] = hh;
            out_l[(size_t)r * D + n] = ll;
        }
    }
}

// ---------------------------------------------------------------------------
// MFMA predictor: out[p] = relu((h2[s]*h2[d]) @ Wp1 + bp1) . Wp2 + bp2
// Z computed fp32 from hi/lo h2, split into swizzled LDS. K=128.
// ---------------------------------------------------------------------------
__global__ void __launch_bounds__(256) mfma_predictor(
    const ushort_t* __restrict__ Hh, const ushort_t* __restrict__ Hl,
    const int* __restrict__ srcI, const int* __restrict__ dstI,
    const ushort_t* __restrict__ Wth, const ushort_t* __restrict__ Wtl,
    const float* __restrict__ bp1,
    const float* __restrict__ Wp2, const float* __restrict__ bp2,
    float* __restrict__ out)
{
    __shared__ short Zh[32 * 128];   // [row][128k] bf16 swizzled (256B rows)
    __shared__ short Zl[32 * 128];
    __shared__ short Bh[128 * 64];
    __shared__ short Bl[128 * 64];
    __shared__ float red[2][32];

    int t = threadIdx.x;
    int l = t & 63, w = t >> 6;
    int rt = w >> 1, ch = w & 1;
    int lrow = l & 15, kg = l >> 4;
    int row0 = blockIdx.x * 32;          // exact: 100000/32 = 3125

    // stage Z = h2[s] * h2[d], split hi/lo, swizzled
    for (int i = 0; i < 4; ++i) {
        int idx = t + i * 256;
        int r = idx >> 5;
        int c4 = (idx & 31) << 2;
        int p = row0 + r;
        int s = srcI[p], d2 = dstI[p];
        ushort4 ah4 = *reinterpret_cast<const ushort4*>(Hh + (size_t)s * D + c4);
        ushort4 al4 = *reinterpret_cast<const ushort4*>(Hl + (size_t)s * D + c4);
        ushort4 bh4 = *reinterpret_cast<const ushort4*>(Hh + (size_t)d2 * D + c4);
        ushort4 bl4 = *reinterpret_cast<const ushort4*>(Hl + (size_t)d2 * D + c4);
        float z0 = (bf2f(ah4.x) + bf2f(al4.x)) * (bf2f(bh4.x) + bf2f(bl4.x));
        float z1 = (bf2f(ah4.y) + bf2f(al4.y)) * (bf2f(bh4.y) + bf2f(bl4.y));
        float z2 = (bf2f(ah4.z) + bf2f(al4.z)) * (bf2f(bh4.z) + bf2f(bl4.z));
        float z3 = (bf2f(ah4.w) + bf2f(al4.w)) * (bf2f(bh4.w) + bf2f(bl4.w));
        ushort4 h4, l4;
        split2(z0, h4.x, l4.x); split2(z1, h4.y, l4.y);
        split2(z2, h4.z, l4.z); split2(z3, h4.w, l4.w);
        int db = r * 256 + ((c4 * 2) ^ ((r & 7) << 4));
        *reinterpret_cast<ushort4*>((char*)Zh + db) = h4;
        *reinterpret_cast<ushort4*>((char*)Zl + db) = l4;
    }

    f32x4 acc[4];
    for (int i = 0; i < 4; ++i) acc[i] = (f32x4)(0.f);

    for (int kc = 0; kc < 2; ++kc) {
        __syncthreads();                 // covers Z writes (kc=0) and B reuse
        for (int i = 0; i < 4; ++i) {
            int s = t + i * 256;
            int n = s >> 3;
            int k8 = (s & 7) * 8;
            short8 vh = *reinterpret_cast<const short8*>(Wth + n * 128 + kc * 64 + k8);
            short8 vl = *reinterpret_cast<const short8*>(Wtl + n * 128 + kc * 64 + k8);
            int db = n * 128 + ((k8 * 2) ^ ((n & 7) << 4));
            *reinterpret_cast<short8*>((char*)Bh + db) = vh;
            *reinterpret_cast<short8*>((char*)Bl + db) = vl;
        }
        __syncthreads();

        for (int ks = 0; ks < 2; ++ks) {
            int zrow = rt * 16 + lrow;
            int kz2 = (kc * 64 + ks * 32 + kg * 8) * 2;    // byte offset in Z row
            int za = zrow * 256 + (kz2 ^ ((zrow & 7) << 4));
            short8 ah = *reinterpret_cast<const short8*>((char*)Zh + za);
            short8 al = *reinterpret_cast<const short8*>((char*)Zl + za);
            int kb2 = (ks * 32 + kg * 8) * 2;
            for (int ct = 0; ct < 4; ++ct) {
                int n = ch * 64 + ct * 16 + lrow;
                int db = n * 128 + (kb2 ^ ((n & 7) << 4));
                short8 bh = *reinterpret_cast<const short8*>((char*)Bh + db);
                short8 bl = *reinterpret_cast<const short8*>((char*)Bl + db);
                acc[ct] = __builtin_amdgcn_mfma_f32_16x16x32_bf16(ah, bh, acc[ct], 0, 0, 0);
                acc[ct] = __builtin_amdgcn_mfma_f32_16x16x32_bf16(ah, bl, acc[ct], 0, 0, 0);
                acc[ct] = __builtin_amdgcn_mfma_f32_16x16x32_bf16(al, bh, acc[ct], 0, 0, 0);
            }
        }
    }

    // epilogue: y = relu(acc + bp1); partial[j] = sum_n y*Wp2[n]
    float partial[4] = {0.f, 0.f, 0.f, 0.f};
    for (int ct = 0; ct < 4; ++ct) {
        int n = ch * 64 + ct * 16 + lrow;
        float bv = bp1[n];
        float w2 = Wp2[n];
        for (int j = 0; j < 4; ++j) {
            float y = acc[ct][j] + bv;
            partial[j] += fmaxf(y, 0.f) * w2;
        }
    }
    for (int j = 0; j < 4; ++j)
        for (int off = 8; off >= 1; off >>= 1)
            partial[j] += __shfl_xor(partial[j], off);
    if (lrow == 0)
        for (int j = 0; j < 4; ++j)
            red[ch][rt * 16 + kg * 4 + j] = partial[j];
    __syncthreads();
    if (t < 32)
        out[row0 + t] = red[0][t] + red[1][t] + bp2[0];
}

// ---------------------------------------------------------------------------
extern "C" void kernel_launch(void* const* d_in, const int* in_sizes, int n_in,
                              void* d_out, int out_size, void* d_ws, size_t ws_size,
                              hipStream_t stream) {
    const float* x   = (const float*)d_in[0];
    const int*   es1 = (const int*)d_in[1];
    const int*   ed1 = (const int*)d_in[2];
    const int*   es2 = (const int*)d_in[3];
    const int*   ed2 = (const int*)d_in[4];
    const int*   ps  = (const int*)d_in[5];
    const int*   pd  = (const int*)d_in[6];
    const int*   ns  = (const int*)d_in[7];
    const int*   nd  = (const int*)d_in[8];
    const float* Ws1 = (const float*)d_in[9];
    const float* Wn1 = (const float*)d_in[10];
    const float* b1  = (const float*)d_in[11];
    const float* Ws2 = (const float*)d_in[12];
    const float* Wn2 = (const float*)d_in[13];
    const float* b2  = (const float*)d_in[14];
    const float* Wp1 = (const float*)d_in[15];
    const float* bp1 = (const float*)d_in[16];
    const float* Wp2 = (const float*)d_in[17];
    const float* bp2 = (const float*)d_in[18];
    float* out = (float*)d_out;

    char* ws = (char*)d_ws;
    size_t half = (size_t)NN * D * sizeof(ushort_t);   // 25.6 MB
    ushort_t* x_h    = (ushort_t*)(ws);                // -> h_h after layer-1 GEMM
    ushort_t* x_l    = (ushort_t*)(ws + half);         // -> h_l
    ushort_t* mean_h = (ushort_t*)(ws + 2 * half);     // -> h2_h after layer-2 GEMM
    ushort_t* mean_l = (ushort_t*)(ws + 3 * half);     // -> h2_l
    ushort_t* w1t_h  = (ushort_t*)(ws + 4 * half);
    ushort_t* w1t_l  = w1t_h + 256 * 128;
    ushort_t* w2t_h  = w1t_l + 256 * 128;
    ushort_t* w2t_l  = w2t_h + 256 * 128;
    ushort_t* wpt_h  = w2t_l + 256 * 128;
    ushort_t* wpt_l  = wpt_h + 128 * 128;
    int* cnt     = (int*)(wpt_l + 128 * 128 + 64);
    int* row_off = cnt + NN;
    int* cursor  = row_off + NN + 1;
    int* csr     = cursor + NN;
    int* bsums   = csr + NE;

    dim3 blk(256);
    int edgeBlocks   = (NE + 255) / 256;
    int gatherBlocks = NN * 32 / 256;    // 12500 exact
    int gemmBlocks   = NN / 32;          // 3125 exact
    int predBlocks   = NP / 32;          // 3125 exact

    // ---- Prep (independent) ----
    convert_x_kernel<<<NN * 32 / 256, blk, 0, stream>>>(x, x_h, x_l);
    prep_wt_kernel<<<128, blk, 0, stream>>>(Ws1, Wn1, w1t_h, w1t_l);
    prep_wt_kernel<<<128, blk, 0, stream>>>(Ws2, Wn2, w2t_h, w2t_l);
    prep_wp_kernel<<<64, blk, 0, stream>>>(Wp1, wpt_h, wpt_l);

    // ---- Layer 1 ----
    hipMemsetAsync(cnt, 0, NN * sizeof(int), stream);
    count_kernel<<<edgeBlocks, blk, 0, stream>>>(ed1, cnt, NE);
    block_sum_kernel<<<NB, blk, 0, stream>>>(cnt, bsums);
    scan_sums_kernel<<<1, 512, 0, stream>>>(bsums);
    block_scan_kernel<<<NB, blk, 0, stream>>>(cnt, bsums, row_off, cursor);
    fill_kernel<<<edgeBlocks, blk, 0, stream>>>(es1, ed1, cursor, csr, NE);
    gather_mean_kernel<<<gatherBlocks, blk, 0, stream>>>(x_h, x_l, row_off, csr, mean_h, mean_l);
    // h (hi/lo) overwrites x (hi/lo): each block reads only its own 32 rows
    // before writing them in the epilogue -> safe.
    mfma_sage_gemm<true><<<gemmBlocks, blk, 0, stream>>>(
        x_h, x_l, mean_h, mean_l, w1t_h, w1t_l, b1, x_h, x_l);

    // ---- Layer 2 ----
    hipMemsetAsync(cnt, 0, NN * sizeof(int), stream);
    count_kernel<<<edgeBlocks, blk, 0, stream>>>(ed2, cnt, NE);
    block_sum_kernel<<<NB, blk, 0, stream>>>(cnt, bsums);
    scan_sums_kernel<<<1, 512, 0, stream>>>(bsums);
    block_scan_kernel<<<NB, blk, 0, stream>>>(cnt, bsums, row_off, cursor);
    fill_kernel<<<edgeBlocks, blk, 0, stream>>>(es2, ed2, cursor, csr, NE);
    gather_mean_kernel<<<gatherBlocks, blk, 0, stream>>>(x_h, x_l, row_off, csr, mean_h, mean_l);
    // h2 (hi/lo) overwrites mean (hi/lo), row-for-row -> safe.
    mfma_sage_gemm<false><<<gemmBlocks, blk, 0, stream>>>(
        x_h, x_l, mean_h, mean_l, w2t_h, w2t_l, b2, mean_h, mean_l);

    // ---- Predictor ----
    mfma_predictor<<<predBlocks, blk, 0, stream>>>(
        mean_h, mean_l, ps, pd, wpt_h, wpt_l, bp1, Wp2, bp2, out);
    mfma_predictor<<<predBlocks, blk, 0, stream>>>(
        mean_h, mean_l, ns, nd, wpt_h, wpt_l, bp1, Wp2, bp2, out + NP);
}

// Round 5
// 551.935 us; speedup vs baseline: 7.0494x; 1.0151x over previous
//
#include <hip/hip_runtime.h>

typedef unsigned short ushort_t;
typedef __attribute__((ext_vector_type(8))) short short8;
typedef __attribute__((ext_vector_type(4))) float f32x4;

// Problem constants
constexpr int NN = 100000;   // nodes
constexpr int D  = 128;      // feature dim
constexpr int NE = 1000000;  // edges per layer
constexpr int NP = 100000;   // pos/neg pairs
constexpr int NB = (NN + 255) / 256;   // scan blocks

// ---------------- bf16 helpers (manual RNE) --------------------------------
__device__ __forceinline__ float bf2f(ushort_t u) {
    union { unsigned int i; float f; } v; v.i = ((unsigned int)u) << 16; return v.f;
}
__device__ __forceinline__ ushort_t f2bf(float x) {
    union { float f; unsigned int i; } v; v.f = x;
    unsigned int r = v.i + 0x7fffu + ((v.i >> 16) & 1u);
    return (ushort_t)(r >> 16);
}
__device__ __forceinline__ void split2(float x, ushort_t& h, ushort_t& l) {
    h = f2bf(x);
    l = f2bf(x - bf2f(h));
}

// ---------------------------------------------------------------------------
// Prep: split x into hi/lo bf16 arrays [NN][128]
// ---------------------------------------------------------------------------
__global__ void __launch_bounds__(256) convert_x_kernel(
    const float* __restrict__ x, ushort_t* __restrict__ xh, ushort_t* __restrict__ xl)
{
    int tid = blockIdx.x * 256 + threadIdx.x;     // NN*32 threads, 4 elems each
    float4 v = *reinterpret_cast<const float4*>(x + (size_t)tid * 4);
    ushort4 h4, l4;
    split2(v.x, h4.x, l4.x); split2(v.y, h4.y, l4.y);
    split2(v.z, h4.z, l4.z); split2(v.w, h4.w, l4.w);
    *reinterpret_cast<ushort4*>(xh + (size_t)tid * 4) = h4;
    *reinterpret_cast<ushort4*>(xl + (size_t)tid * 4) = l4;
}

// ---------------------------------------------------------------------------
// Prep: W = [Wself; Wneigh] (256k x 128n) -> transposed hi/lo [128n][256k]
// ---------------------------------------------------------------------------
__global__ void __launch_bounds__(256) prep_wt_kernel(
    const float* __restrict__ Ws, const float* __restrict__ Wn,
    ushort_t* __restrict__ Wth, ushort_t* __restrict__ Wtl)
{
    int tid = blockIdx.x * 256 + threadIdx.x;   // 32768 threads
    int k = tid >> 7, n = tid & 127;
    float v = (k < 128) ? Ws[k * 128 + n] : Wn[(k - 128) * 128 + n];
    ushort_t h, l; split2(v, h, l);
    Wth[n * 256 + k] = h; Wtl[n * 256 + k] = l;
}

// Wp1 (128x128) -> transposed hi/lo [128n][128k]
__global__ void __launch_bounds__(256) prep_wp_kernel(
    const float* __restrict__ Wp1, ushort_t* __restrict__ Wth, ushort_t* __restrict__ Wtl)
{
    int tid = blockIdx.x * 256 + threadIdx.x;   // 16384 threads
    int k = tid >> 7, n = tid & 127;
    float v = Wp1[k * 128 + n];
    ushort_t h, l; split2(v, h, l);
    Wth[n * 128 + k] = h; Wtl[n * 128 + k] = l;
}

// ---------------------------------------------------------------------------
// CSR build
// ---------------------------------------------------------------------------
__global__ void __launch_bounds__(256) count_kernel(
    const int* __restrict__ dst, int* __restrict__ cnt, int nE)
{
    int e = blockIdx.x * blockDim.x + threadIdx.x;
    if (e >= nE) return;
    atomicAdd(&cnt[dst[e]], 1);
}

__global__ void __launch_bounds__(256) block_sum_kernel(
    const int* __restrict__ cnt, int* __restrict__ bsums)
{
    __shared__ int red[4];
    int i = blockIdx.x * 256 + threadIdx.x;
    int v = (i < NN) ? cnt[i] : 0;
    for (int off = 32; off >= 1; off >>= 1) v += __shfl_xor(v, off);
    int wave = threadIdx.x >> 6;
    if ((threadIdx.x & 63) == 0) red[wave] = v;
    __syncthreads();
    if (threadIdx.x == 0)
        bsums[blockIdx.x] = red[0] + red[1] + red[2] + red[3];
}

__global__ void __launch_bounds__(512) scan_sums_kernel(int* __restrict__ bsums)
{
    __shared__ int s[512];
    int t = threadIdx.x;
    int v = (t < NB) ? bsums[t] : 0;
    s[t] = v;
    __syncthreads();
    for (int off = 1; off < 512; off <<= 1) {
        int u = (t >= off) ? s[t - off] : 0;
        __syncthreads();
        s[t] += u;
        __syncthreads();
    }
    if (t < NB) bsums[t] = s[t] - v;
}

__global__ void __launch_bounds__(256) block_scan_kernel(
    const int* __restrict__ cnt, const int* __restrict__ bsums,
    int* __restrict__ row_off, int* __restrict__ cursor)
{
    __shared__ int s[256];
    int t = threadIdx.x;
    int i = blockIdx.x * 256 + t;
    int v = (i < NN) ? cnt[i] : 0;
    s[t] = v;
    __syncthreads();
    for (int off = 1; off < 256; off <<= 1) {
        int u = (t >= off) ? s[t - off] : 0;
        __syncthreads();
        s[t] += u;
        __syncthreads();
    }
    int ex = s[t] - v + bsums[blockIdx.x];
    if (i < NN) { row_off[i] = ex; cursor[i] = ex; }
    if (i == 0) row_off[NN] = NE;
}

__global__ void __launch_bounds__(256) fill_kernel(
    const int* __restrict__ src, const int* __restrict__ dst,
    int* __restrict__ cursor, int* __restrict__ csr, int nE)
{
    int e = blockIdx.x * blockDim.x + threadIdx.x;
    if (e >= nE) return;
    int pos = atomicAdd(&cursor[dst[e]], 1);
    csr[pos] = src[e];
}

// ---------------------------------------------------------------------------
// Gather-mean from FP32 features, 4x unrolled for MLP (memory-level parallel):
// 4 independent csr loads then 4 independent 16B row loads in flight per lane.
// Emits hi/lo bf16 mean (split once per node).
// ---------------------------------------------------------------------------
__global__ void __launch_bounds__(256) gather_mean_kernel(
    const float* __restrict__ feat,
    const int* __restrict__ row_off,
    const int* __restrict__ csr,
    ushort_t* __restrict__ mh, ushort_t* __restrict__ ml)
{
    int tid = blockIdx.x * 256 + threadIdx.x;
    int g = tid >> 5;
    int lane = tid & 31;
    int c = lane << 2;
    int beg = row_off[g], end = row_off[g + 1];
    float ax0 = 0.f, ay0 = 0.f, az0 = 0.f, aw0 = 0.f;
    float ax1 = 0.f, ay1 = 0.f, az1 = 0.f, aw1 = 0.f;
    int j = beg;
    for (; j + 4 <= end; j += 4) {
        int s0 = csr[j + 0], s1 = csr[j + 1], s2 = csr[j + 2], s3 = csr[j + 3];
        float4 v0 = *reinterpret_cast<const float4*>(feat + (size_t)s0 * D + c);
        float4 v1 = *reinterpret_cast<const float4*>(feat + (size_t)s1 * D + c);
        float4 v2 = *reinterpret_cast<const float4*>(feat + (size_t)s2 * D + c);
        float4 v3 = *reinterpret_cast<const float4*>(feat + (size_t)s3 * D + c);
        ax0 += v0.x + v1.x; ay0 += v0.y + v1.y;
        az0 += v0.z + v1.z; aw0 += v0.w + v1.w;
        ax1 += v2.x + v3.x; ay1 += v2.y + v3.y;
        az1 += v2.z + v3.z; aw1 += v2.w + v3.w;
    }
    for (; j < end; ++j) {
        int s = csr[j];
        float4 v = *reinterpret_cast<const float4*>(feat + (size_t)s * D + c);
        ax0 += v.x; ay0 += v.y; az0 += v.z; aw0 += v.w;
    }
    float rd = 1.0f / fmaxf((float)(end - beg), 1.0f);
    float mx = (ax0 + ax1) * rd, my = (ay0 + ay1) * rd;
    float mz = (az0 + az1) * rd, mw = (aw0 + aw1) * rd;
    ushort4 h4, l4;
    split2(mx, h4.x, l4.x); split2(my, h4.y, l4.y);
    split2(mz, h4.z, l4.z); split2(mw, h4.w, l4.w);
    *reinterpret_cast<ushort4*>(mh + (size_t)g * D + c) = h4;
    *reinterpret_cast<ushort4*>(ml + (size_t)g * D + c) = l4;
}

// ---------------------------------------------------------------------------
// MFMA split-bf16 SAGEConv GEMM (as R4), with configurable epilogue:
// WSPLIT -> write hi/lo bf16; WF32 -> write fp32.
// ---------------------------------------------------------------------------
template<bool RELU, bool WSPLIT, bool WF32>
__global__ void __launch_bounds__(256) mfma_sage_gemm(
    const ushort_t* __restrict__ Ah_self, const ushort_t* __restrict__ Al_self,
    const ushort_t* __restrict__ Ah_nei,  const ushort_t* __restrict__ Al_nei,
    const ushort_t* __restrict__ Wth, const ushort_t* __restrict__ Wtl,
    const float* __restrict__ bias,
    ushort_t* __restrict__ out_h, ushort_t* __restrict__ out_l,
    float* __restrict__ out_f)
{
    __shared__ short Bh[128 * 64];   // [n][64k] bf16, swizzled
    __shared__ short Bl[128 * 64];

    int t = threadIdx.x;
    int l = t & 63, w = t >> 6;
    int rt = w >> 1, ch = w & 1;
    int lrow = l & 15, kg = l >> 4;
    int row0 = blockIdx.x * 32;
    int arow = row0 + rt * 16 + lrow;

    f32x4 acc[4];
    for (int i = 0; i < 4; ++i) acc[i] = (f32x4)(0.f);

    for (int half = 0; half < 2; ++half) {
        const ushort_t* Ah = half ? Ah_nei : Ah_self;
        const ushort_t* Al = half ? Al_nei : Al_self;
        for (int kc2 = 0; kc2 < 2; ++kc2) {
            int kcat = half * 128 + kc2 * 64;
            __syncthreads();
            for (int i = 0; i < 4; ++i) {
                int s = t + i * 256;
                int n = s >> 3;
                int k8 = (s & 7) * 8;
                short8 vh = *reinterpret_cast<const short8*>(Wth + n * 256 + kcat + k8);
                short8 vl = *reinterpret_cast<const short8*>(Wtl + n * 256 + kcat + k8);
                int db = n * 128 + ((k8 * 2) ^ ((n & 7) << 4));
                *reinterpret_cast<short8*>((char*)Bh + db) = vh;
                *reinterpret_cast<short8*>((char*)Bl + db) = vl;
            }
            __syncthreads();

            for (int ks = 0; ks < 2; ++ks) {
                int ka = kc2 * 64 + ks * 32 + kg * 8;
                short8 ah = *reinterpret_cast<const short8*>(Ah + (size_t)arow * D + ka);
                short8 al = *reinterpret_cast<const short8*>(Al + (size_t)arow * D + ka);
                int kb2 = (ks * 32 + kg * 8) * 2;
                for (int ct = 0; ct < 4; ++ct) {
                    int n = ch * 64 + ct * 16 + lrow;
                    int db = n * 128 + (kb2 ^ ((n & 7) << 4));
                    short8 bh = *reinterpret_cast<const short8*>((char*)Bh + db);
                    short8 bl = *reinterpret_cast<const short8*>((char*)Bl + db);
                    acc[ct] = __builtin_amdgcn_mfma_f32_16x16x32_bf16(ah, bh, acc[ct], 0, 0, 0);
                    acc[ct] = __builtin_amdgcn_mfma_f32_16x16x32_bf16(ah, bl, acc[ct], 0, 0, 0);
                    acc[ct] = __builtin_amdgcn_mfma_f32_16x16x32_bf16(al, bh, acc[ct], 0, 0, 0);
                }
            }
        }
    }

    // epilogue: C/D layout col = lane&15, row = (lane>>4)*4 + j
    for (int ct = 0; ct < 4; ++ct) {
        int n = ch * 64 + ct * 16 + lrow;
        float bv = bias[n];
        for (int j = 0; j < 4; ++j) {
            int r = row0 + rt * 16 + kg * 4 + j;
            float y = acc[ct][j] + bv;
            if (RELU) y = fmaxf(y, 0.f);
            if (WF32) out_f[(size_t)r * D + n] = y;
            if (WSPLIT) {
                ushort_t hh, ll; split2(y, hh, ll);
                out_h[(size_t)r * D + n] = hh;
                out_l[(size_t)r * D + n] = ll;
            }
        }
    }
}

// ---------------------------------------------------------------------------
// MFMA predictor: out[p] = relu((h2[s]*h2[d]) @ Wp1 + bp1) . Wp2 + bp2
// h2 read as fp32 rows; Z split into swizzled LDS. K=128.
// ---------------------------------------------------------------------------
__global__ void __launch_bounds__(256) mfma_predictor(
    const float* __restrict__ H,
    const int* __restrict__ srcI, const int* __restrict__ dstI,
    const ushort_t* __restrict__ Wth, const ushort_t* __restrict__ Wtl,
    const float* __restrict__ bp1,
    const float* __restrict__ Wp2, const float* __restrict__ bp2,
    float* __restrict__ out)
{
    __shared__ short Zh[32 * 128];
    __shared__ short Zl[32 * 128];
    __shared__ short Bh[128 * 64];
    __shared__ short Bl[128 * 64];
    __shared__ float red[2][32];

    int t = threadIdx.x;
    int l = t & 63, w = t >> 6;
    int rt = w >> 1, ch = w & 1;
    int lrow = l & 15, kg = l >> 4;
    int row0 = blockIdx.x * 32;

    for (int i = 0; i < 4; ++i) {
        int idx = t + i * 256;
        int r = idx >> 5;
        int c4 = (idx & 31) << 2;
        int p = row0 + r;
        int s = srcI[p], d2 = dstI[p];
        float4 a = *reinterpret_cast<const float4*>(H + (size_t)s * D + c4);
        float4 b = *reinterpret_cast<const float4*>(H + (size_t)d2 * D + c4);
        float z0 = a.x * b.x, z1 = a.y * b.y, z2 = a.z * b.z, z3 = a.w * b.w;
        ushort4 h4, l4;
        split2(z0, h4.x, l4.x); split2(z1, h4.y, l4.y);
        split2(z2, h4.z, l4.z); split2(z3, h4.w, l4.w);
        int db = r * 256 + ((c4 * 2) ^ ((r & 7) << 4));
        *reinterpret_cast<ushort4*>((char*)Zh + db) = h4;
        *reinterpret_cast<ushort4*>((char*)Zl + db) = l4;
    }

    f32x4 acc[4];
    for (int i = 0; i < 4; ++i) acc[i] = (f32x4)(0.f);

    for (int kc = 0; kc < 2; ++kc) {
        __syncthreads();
        for (int i = 0; i < 4; ++i) {
            int s = t + i * 256;
            int n = s >> 3;
            int k8 = (s & 7) * 8;
            short8 vh = *reinterpret_cast<const short8*>(Wth + n * 128 + kc * 64 + k8);
            short8 vl = *reinterpret_cast<const short8*>(Wtl + n * 128 + kc * 64 + k8);
            int db = n * 128 + ((k8 * 2) ^ ((n & 7) << 4));
            *reinterpret_cast<short8*>((char*)Bh + db) = vh;
            *reinterpret_cast<short8*>((char*)Bl + db) = vl;
        }
        __syncthreads();

        for (int ks = 0; ks < 2; ++ks) {
            int zrow = rt * 16 + lrow;
            int kz2 = (kc * 64 + ks * 32 + kg * 8) * 2;
            int za = zrow * 256 + (kz2 ^ ((zrow & 7) << 4));
            short8 ah = *reinterpret_cast<const short8*>((char*)Zh + za);
            short8 al = *reinterpret_cast<const short8*>((char*)Zl + za);
            int kb2 = (ks * 32 + kg * 8) * 2;
            for (int ct = 0; ct < 4; ++ct) {
                int n = ch * 64 + ct * 16 + lrow;
                int db = n * 128 + (kb2 ^ ((n & 7) << 4));
                short8 bh = *reinterpret_cast<const short8*>((char*)Bh + db);
                short8 bl = *reinterpret_cast<const short8*>((char*)Bl + db);
                acc[ct] = __builtin_amdgcn_mfma_f32_16x16x32_bf16(ah, bh, acc[ct], 0, 0, 0);
                acc[ct] = __builtin_amdgcn_mfma_f32_16x16x32_bf16(ah, bl, acc[ct], 0, 0, 0);
                acc[ct] = __builtin_amdgcn_mfma_f32_16x16x32_bf16(al, bh, acc[ct], 0, 0, 0);
            }
        }
    }

    float partial[4] = {0.f, 0.f, 0.f, 0.f};
    for (int ct = 0; ct < 4; ++ct) {
        int n = ch * 64 + ct * 16 + lrow;
        float bv = bp1[n];
        float w2 = Wp2[n];
        for (int j = 0; j < 4; ++j) {
            float y = acc[ct][j] + bv;
            partial[j] += fmaxf(y, 0.f) * w2;
        }
    }
    for (int j = 0; j < 4; ++j)
        for (int off = 8; off >= 1; off >>= 1)
            partial[j] += __shfl_xor(partial[j], off);
    if (lrow == 0)
        for (int j = 0; j < 4; ++j)
            red[ch][rt * 16 + kg * 4 + j] = partial[j];
    __syncthreads();
    if (t < 32)
        out[row0 + t] = red[0][t] + red[1][t] + bp2[0];
}

// ---------------------------------------------------------------------------
extern "C" void kernel_launch(void* const* d_in, const int* in_sizes, int n_in,
                              void* d_out, int out_size, void* d_ws, size_t ws_size,
                              hipStream_t stream) {
    const float* x   = (const float*)d_in[0];
    const int*   es1 = (const int*)d_in[1];
    const int*   ed1 = (const int*)d_in[2];
    const int*   es2 = (const int*)d_in[3];
    const int*   ed2 = (const int*)d_in[4];
    const int*   ps  = (const int*)d_in[5];
    const int*   pd  = (const int*)d_in[6];
    const int*   ns  = (const int*)d_in[7];
    const int*   nd  = (const int*)d_in[8];
    const float* Ws1 = (const float*)d_in[9];
    const float* Wn1 = (const float*)d_in[10];
    const float* b1  = (const float*)d_in[11];
    const float* Ws2 = (const float*)d_in[12];
    const float* Wn2 = (const float*)d_in[13];
    const float* b2  = (const float*)d_in[14];
    const float* Wp1 = (const float*)d_in[15];
    const float* bp1 = (const float*)d_in[16];
    const float* Wp2 = (const float*)d_in[17];
    const float* bp2 = (const float*)d_in[18];
    float* out = (float*)d_out;

    char* ws = (char*)d_ws;
    size_t halfb = (size_t)NN * D * sizeof(ushort_t);  // 25.6 MB
    ushort_t* x_h    = (ushort_t*)(ws);                // -> h_h after layer-1 GEMM
    ushort_t* x_l    = (ushort_t*)(ws + halfb);        // -> h_l
    ushort_t* mean_h = (ushort_t*)(ws + 2 * halfb);
    ushort_t* mean_l = (ushort_t*)(ws + 3 * halfb);
    float*    hf     = (float*)(ws + 4 * halfb);       // fp32 h; later fp32 h2
    char* wsp = ws + 4 * halfb + (size_t)NN * D * sizeof(float);
    ushort_t* w1t_h  = (ushort_t*)wsp;
    ushort_t* w1t_l  = w1t_h + 256 * 128;
    ushort_t* w2t_h  = w1t_l + 256 * 128;
    ushort_t* w2t_l  = w2t_h + 256 * 128;
    ushort_t* wpt_h  = w2t_l + 256 * 128;
    ushort_t* wpt_l  = wpt_h + 128 * 128;
    int* cnt     = (int*)(wpt_l + 128 * 128 + 64);
    int* row_off = cnt + NN;
    int* cursor  = row_off + NN + 1;
    int* csr     = cursor + NN;
    int* bsums   = csr + NE;

    dim3 blk(256);
    int edgeBlocks   = (NE + 255) / 256;
    int gatherBlocks = NN * 32 / 256;    // 12500 exact
    int gemmBlocks   = NN / 32;          // 3125 exact
    int predBlocks   = NP / 32;          // 3125 exact

    // ---- Prep ----
    convert_x_kernel<<<NN * 32 / 256, blk, 0, stream>>>(x, x_h, x_l);
    prep_wt_kernel<<<128, blk, 0, stream>>>(Ws1, Wn1, w1t_h, w1t_l);
    prep_wt_kernel<<<128, blk, 0, stream>>>(Ws2, Wn2, w2t_h, w2t_l);
    prep_wp_kernel<<<64, blk, 0, stream>>>(Wp1, wpt_h, wpt_l);

    // ---- Layer 1 ----
    hipMemsetAsync(cnt, 0, NN * sizeof(int), stream);
    count_kernel<<<edgeBlocks, blk, 0, stream>>>(ed1, cnt, NE);
    block_sum_kernel<<<NB, blk, 0, stream>>>(cnt, bsums);
    scan_sums_kernel<<<1, 512, 0, stream>>>(bsums);
    block_scan_kernel<<<NB, blk, 0, stream>>>(cnt, bsums, row_off, cursor);
    fill_kernel<<<edgeBlocks, blk, 0, stream>>>(es1, ed1, cursor, csr, NE);
    gather_mean_kernel<<<gatherBlocks, blk, 0, stream>>>(x, row_off, csr, mean_h, mean_l);
    // writes h hi/lo in place over x_h/x_l (block-local rows) + fp32 h to hf
    mfma_sage_gemm<true, true, true><<<gemmBlocks, blk, 0, stream>>>(
        x_h, x_l, mean_h, mean_l, w1t_h, w1t_l, b1, x_h, x_l, hf);

    // ---- Layer 2 ----
    hipMemsetAsync(cnt, 0, NN * sizeof(int), stream);
    count_kernel<<<edgeBlocks, blk, 0, stream>>>(ed2, cnt, NE);
    block_sum_kernel<<<NB, blk, 0, stream>>>(cnt, bsums);
    scan_sums_kernel<<<1, 512, 0, stream>>>(bsums);
    block_scan_kernel<<<NB, blk, 0, stream>>>(cnt, bsums, row_off, cursor);
    fill_kernel<<<edgeBlocks, blk, 0, stream>>>(es2, ed2, cursor, csr, NE);
    gather_mean_kernel<<<gatherBlocks, blk, 0, stream>>>(hf, row_off, csr, mean_h, mean_l);
    // h2 fp32 overwrites hf (dead after the gather above); GEMM doesn't read hf
    mfma_sage_gemm<false, false, true><<<gemmBlocks, blk, 0, stream>>>(
        x_h, x_l, mean_h, mean_l, w2t_h, w2t_l, b2, nullptr, nullptr, hf);

    // ---- Predictor ----
    mfma_predictor<<<predBlocks, blk, 0, stream>>>(
        hf, ps, pd, wpt_h, wpt_l, bp1, Wp2, bp2, out);
    mfma_predictor<<<predBlocks, blk, 0, stream>>>(
        hf, ns, nd, wpt_h, wpt_l, bp1, Wp2, bp2, out + NP);
}

// Round 6
// 551.737 us; speedup vs baseline: 7.0520x; 1.0004x over previous
//
#include <hip/hip_runtime.h>

typedef unsigned short ushort_t;
typedef __attribute__((ext_vector_type(8))) short short8;
typedef __attribute__((ext_vector_type(4))) float f32x4;

// Problem constants
constexpr int NN = 100000;   // nodes
constexpr int D  = 128;      // feature dim
constexpr int NE = 1000000;  // edges per layer
constexpr int NP = 100000;   // pos/neg pairs
constexpr int NB2 = (2 * NN + 255) / 256;   // 782 scan blocks over both layers

// ---------------- bf16 helpers (manual RNE) --------------------------------
__device__ __forceinline__ float bf2f(ushort_t u) {
    union { unsigned int i; float f; } v; v.i = ((unsigned int)u) << 16; return v.f;
}
__device__ __forceinline__ ushort_t f2bf(float x) {
    union { float f; unsigned int i; } v; v.f = x;
    unsigned int r = v.i + 0x7fffu + ((v.i >> 16) & 1u);
    return (ushort_t)(r >> 16);
}
__device__ __forceinline__ void split2(float x, ushort_t& h, ushort_t& l) {
    h = f2bf(x);
    l = f2bf(x - bf2f(h));
}

// ---------------------------------------------------------------------------
// Fused prep: convert x -> hi/lo bf16 [NN][128]; transpose+split all weights.
// Block ranges: [0,12500) convert_x; [12500,12628) W1; [12628,12756) W2;
// [12756,12820) Wp1.
// ---------------------------------------------------------------------------
__global__ void __launch_bounds__(256) prep_kernel(
    const float* __restrict__ x,
    const float* __restrict__ Ws1, const float* __restrict__ Wn1,
    const float* __restrict__ Ws2, const float* __restrict__ Wn2,
    const float* __restrict__ Wp1,
    ushort_t* __restrict__ xh, ushort_t* __restrict__ xl,
    ushort_t* __restrict__ w1h, ushort_t* __restrict__ w1l,
    ushort_t* __restrict__ w2h, ushort_t* __restrict__ w2l,
    ushort_t* __restrict__ wph, ushort_t* __restrict__ wpl)
{
    int b = blockIdx.x;
    if (b < 12500) {
        int tid = b * 256 + threadIdx.x;
        float4 v = *reinterpret_cast<const float4*>(x + (size_t)tid * 4);
        ushort4 h4, l4;
        split2(v.x, h4.x, l4.x); split2(v.y, h4.y, l4.y);
        split2(v.z, h4.z, l4.z); split2(v.w, h4.w, l4.w);
        *reinterpret_cast<ushort4*>(xh + (size_t)tid * 4) = h4;
        *reinterpret_cast<ushort4*>(xl + (size_t)tid * 4) = l4;
    } else if (b < 12756) {
        int layer2 = (b >= 12628);
        int tid = (b - (layer2 ? 12628 : 12500)) * 256 + threadIdx.x;  // 32768
        int k = tid >> 7, n = tid & 127;
        const float* Ws = layer2 ? Ws2 : Ws1;
        const float* Wn = layer2 ? Wn2 : Wn1;
        ushort_t* Wth = layer2 ? w2h : w1h;
        ushort_t* Wtl = layer2 ? w2l : w1l;
        float v = (k < 128) ? Ws[k * 128 + n] : Wn[(k - 128) * 128 + n];
        ushort_t h, l; split2(v, h, l);
        Wth[n * 256 + k] = h; Wtl[n * 256 + k] = l;
    } else {
        int tid = (b - 12756) * 256 + threadIdx.x;   // 16384
        int k = tid >> 7, n = tid & 127;
        float v = Wp1[k * 128 + n];
        ushort_t h, l; split2(v, h, l);
        wph[n * 128 + k] = h; wpl[n * 128 + k] = l;
    }
}

// ---------------------------------------------------------------------------
// CSR build for BOTH layers in one pass (counts/offsets concatenated 2*NN,
// csr concatenated 2*NE with absolute offsets).
// ---------------------------------------------------------------------------
__global__ void __launch_bounds__(256) count2_kernel(
    const int* __restrict__ ed1, const int* __restrict__ ed2,
    int* __restrict__ cnt)
{
    int e = blockIdx.x * 256 + threadIdx.x;
    if (e >= 2 * NE) return;
    int layer2 = (e >= NE);
    int d = layer2 ? ed2[e - NE] : ed1[e];
    atomicAdd(&cnt[d + (layer2 ? NN : 0)], 1);
}

__global__ void __launch_bounds__(256) block_sum_kernel(
    const int* __restrict__ cnt, int* __restrict__ bsums)
{
    __shared__ int red[4];
    int i = blockIdx.x * 256 + threadIdx.x;
    int v = (i < 2 * NN) ? cnt[i] : 0;
    for (int off = 32; off >= 1; off >>= 1) v += __shfl_xor(v, off);
    int wave = threadIdx.x >> 6;
    if ((threadIdx.x & 63) == 0) red[wave] = v;
    __syncthreads();
    if (threadIdx.x == 0)
        bsums[blockIdx.x] = red[0] + red[1] + red[2] + red[3];
}

__global__ void __launch_bounds__(1024) scan_sums_kernel(int* __restrict__ bsums)
{
    __shared__ int s[1024];
    int t = threadIdx.x;
    int v = (t < NB2) ? bsums[t] : 0;
    s[t] = v;
    __syncthreads();
    for (int off = 1; off < 1024; off <<= 1) {
        int u = (t >= off) ? s[t - off] : 0;
        __syncthreads();
        s[t] += u;
        __syncthreads();
    }
    if (t < NB2) bsums[t] = s[t] - v;
}

__global__ void __launch_bounds__(256) block_scan_kernel(
    const int* __restrict__ cnt, const int* __restrict__ bsums,
    int* __restrict__ row_off, int* __restrict__ cursor)
{
    __shared__ int s[256];
    int t = threadIdx.x;
    int i = blockIdx.x * 256 + t;
    int v = (i < 2 * NN) ? cnt[i] : 0;
    s[t] = v;
    __syncthreads();
    for (int off = 1; off < 256; off <<= 1) {
        int u = (t >= off) ? s[t - off] : 0;
        __syncthreads();
        s[t] += u;
        __syncthreads();
    }
    int ex = s[t] - v + bsums[blockIdx.x];
    if (i < 2 * NN) { row_off[i] = ex; cursor[i] = ex; }
    if (i == 0) row_off[2 * NN] = 2 * NE;   // end sentinel (row_off[NN]=NE implicit)
}

__global__ void __launch_bounds__(256) fill2_kernel(
    const int* __restrict__ es1, const int* __restrict__ ed1,
    const int* __restrict__ es2, const int* __restrict__ ed2,
    int* __restrict__ cursor, int* __restrict__ csr)
{
    int e = blockIdx.x * 256 + threadIdx.x;
    if (e >= 2 * NE) return;
    int layer2 = (e >= NE);
    int s = layer2 ? es2[e - NE] : es1[e];
    int d = layer2 ? ed2[e - NE] : ed1[e];
    int pos = atomicAdd(&cursor[d + (layer2 ? NN : 0)], 1);
    csr[pos] = s;
}

// ---------------------------------------------------------------------------
// Gather-mean from FP32 features, 8x unrolled (deep MLP).
// Emits hi/lo bf16 mean.
// ---------------------------------------------------------------------------
__global__ void __launch_bounds__(256) gather_mean_kernel(
    const float* __restrict__ feat,
    const int* __restrict__ row_off,
    const int* __restrict__ csr,
    ushort_t* __restrict__ mh, ushort_t* __restrict__ ml)
{
    int tid = blockIdx.x * 256 + threadIdx.x;
    int g = tid >> 5;
    int lane = tid & 31;
    int c = lane << 2;
    int beg = row_off[g], end = row_off[g + 1];
    float ax0 = 0.f, ay0 = 0.f, az0 = 0.f, aw0 = 0.f;
    float ax1 = 0.f, ay1 = 0.f, az1 = 0.f, aw1 = 0.f;
    int j = beg;
    for (; j + 8 <= end; j += 8) {
        int s0 = csr[j + 0], s1 = csr[j + 1], s2 = csr[j + 2], s3 = csr[j + 3];
        int s4 = csr[j + 4], s5 = csr[j + 5], s6 = csr[j + 6], s7 = csr[j + 7];
        float4 v0 = *reinterpret_cast<const float4*>(feat + (size_t)s0 * D + c);
        float4 v1 = *reinterpret_cast<const float4*>(feat + (size_t)s1 * D + c);
        float4 v2 = *reinterpret_cast<const float4*>(feat + (size_t)s2 * D + c);
        float4 v3 = *reinterpret_cast<const float4*>(feat + (size_t)s3 * D + c);
        float4 v4 = *reinterpret_cast<const float4*>(feat + (size_t)s4 * D + c);
        float4 v5 = *reinterpret_cast<const float4*>(feat + (size_t)s5 * D + c);
        float4 v6 = *reinterpret_cast<const float4*>(feat + (size_t)s6 * D + c);
        float4 v7 = *reinterpret_cast<const float4*>(feat + (size_t)s7 * D + c);
        ax0 += v0.x + v1.x + v4.x + v5.x; ay0 += v0.y + v1.y + v4.y + v5.y;
        az0 += v0.z + v1.z + v4.z + v5.z; aw0 += v0.w + v1.w + v4.w + v5.w;
        ax1 += v2.x + v3.x + v6.x + v7.x; ay1 += v2.y + v3.y + v6.y + v7.y;
        az1 += v2.z + v3.z + v6.z + v7.z; aw1 += v2.w + v3.w + v6.w + v7.w;
    }
    for (; j < end; ++j) {
        int s = csr[j];
        float4 v = *reinterpret_cast<const float4*>(feat + (size_t)s * D + c);
        ax0 += v.x; ay0 += v.y; az0 += v.z; aw0 += v.w;
    }
    float rd = 1.0f / fmaxf((float)(end - beg), 1.0f);
    float mx = (ax0 + ax1) * rd, my = (ay0 + ay1) * rd;
    float mz = (az0 + az1) * rd, mw = (aw0 + aw1) * rd;
    ushort4 h4, l4;
    split2(mx, h4.x, l4.x); split2(my, h4.y, l4.y);
    split2(mz, h4.z, l4.z); split2(mw, h4.w, l4.w);
    *reinterpret_cast<ushort4*>(mh + (size_t)g * D + c) = h4;
    *reinterpret_cast<ushort4*>(ml + (size_t)g * D + c) = l4;
}

// ---------------------------------------------------------------------------
// MFMA split-bf16 SAGEConv GEMM, 128 rows/block, 8 waves (one 16-row tile
// each, full 128 cols). Weights staged per 64-k chunk, shared by all 8 waves.
// ---------------------------------------------------------------------------
template<bool RELU, bool WSPLIT, bool WF32>
__global__ void __launch_bounds__(512) mfma_sage_gemm(
    const ushort_t* __restrict__ Ah_self, const ushort_t* __restrict__ Al_self,
    const ushort_t* __restrict__ Ah_nei,  const ushort_t* __restrict__ Al_nei,
    const ushort_t* __restrict__ Wth, const ushort_t* __restrict__ Wtl,
    const float* __restrict__ bias,
    ushort_t* __restrict__ out_h, ushort_t* __restrict__ out_l,
    float* __restrict__ out_f)
{
    __shared__ short Bh[128 * 64];   // [n][64k] bf16, swizzled
    __shared__ short Bl[128 * 64];

    int t = threadIdx.x;
    int l = t & 63, w = t >> 6;      // 8 waves; wave = row-tile
    int lrow = l & 15, kg = l >> 4;
    int row0 = blockIdx.x * 128;
    int arow = row0 + w * 16 + lrow;
    int arow_c = min(arow, NN - 1);  // clamp for tail block loads

    f32x4 acc[8];
    for (int i = 0; i < 8; ++i) acc[i] = (f32x4)(0.f);

    for (int half = 0; half < 2; ++half) {
        const ushort_t* Ah = half ? Ah_nei : Ah_self;
        const ushort_t* Al = half ? Al_nei : Al_self;
        for (int kc2 = 0; kc2 < 2; ++kc2) {
            int kcat = half * 128 + kc2 * 64;
            __syncthreads();
            for (int i = 0; i < 2; ++i) {
                int s = t + i * 512;            // 1024 b128 slots per array
                int n = s >> 3;
                int k8 = (s & 7) * 8;
                short8 vh = *reinterpret_cast<const short8*>(Wth + n * 256 + kcat + k8);
                short8 vl = *reinterpret_cast<const short8*>(Wtl + n * 256 + kcat + k8);
                int db = n * 128 + ((k8 * 2) ^ ((n & 7) << 4));
                *reinterpret_cast<short8*>((char*)Bh + db) = vh;
                *reinterpret_cast<short8*>((char*)Bl + db) = vl;
            }
            __syncthreads();

            for (int ks = 0; ks < 2; ++ks) {
                int ka = kc2 * 64 + ks * 32 + kg * 8;
                short8 ah = *reinterpret_cast<const short8*>(Ah + (size_t)arow_c * D + ka);
                short8 al = *reinterpret_cast<const short8*>(Al + (size_t)arow_c * D + ka);
                int kb2 = (ks * 32 + kg * 8) * 2;
                for (int ct = 0; ct < 8; ++ct) {
                    int n = ct * 16 + lrow;
                    int db = n * 128 + (kb2 ^ ((n & 7) << 4));
                    short8 bh = *reinterpret_cast<const short8*>((char*)Bh + db);
                    short8 bl = *reinterpret_cast<const short8*>((char*)Bl + db);
                    acc[ct] = __builtin_amdgcn_mfma_f32_16x16x32_bf16(ah, bh, acc[ct], 0, 0, 0);
                    acc[ct] = __builtin_amdgcn_mfma_f32_16x16x32_bf16(ah, bl, acc[ct], 0, 0, 0);
                    acc[ct] = __builtin_amdgcn_mfma_f32_16x16x32_bf16(al, bh, acc[ct], 0, 0, 0);
                }
            }
        }
    }

    // epilogue: C/D layout col = lane&15, row = (lane>>4)*4 + j
    for (int ct = 0; ct < 8; ++ct) {
        int n = ct * 16 + lrow;
        float bv = bias[n];
        for (int j = 0; j < 4; ++j) {
            int r = row0 + w * 16 + kg * 4 + j;
            if (r >= NN) continue;
            float y = acc[ct][j] + bv;
            if (RELU) y = fmaxf(y, 0.f);
            if (WF32) out_f[(size_t)r * D + n] = y;
            if (WSPLIT) {
                ushort_t hh, ll; split2(y, hh, ll);
                out_h[(size_t)r * D + n] = hh;
                out_l[(size_t)r * D + n] = ll;
            }
        }
    }
}

// ---------------------------------------------------------------------------
// MFMA predictor, merged pos+neg: 64 pairs/block, 8 waves
// (4 row-tiles x 2 col-halves). p < NP -> pos pair, else neg.
// ---------------------------------------------------------------------------
__global__ void __launch_bounds__(512) mfma_predictor(
    const float* __restrict__ H,
    const int* __restrict__ ps, const int* __restrict__ pd,
    const int* __restrict__ ns, const int* __restrict__ nd,
    const ushort_t* __restrict__ Wth, const ushort_t* __restrict__ Wtl,
    const float* __restrict__ bp1,
    const float* __restrict__ Wp2, const float* __restrict__ bp2,
    float* __restrict__ out)
{
    __shared__ short Zh[64 * 128];   // [row][128k] bf16 swizzled (256B rows)
    __shared__ short Zl[64 * 128];
    __shared__ short Bh[128 * 64];
    __shared__ short Bl[128 * 64];
    __shared__ float red[2][64];

    int t = threadIdx.x;
    int l = t & 63, w = t >> 6;
    int rt = w >> 1, ch = w & 1;
    int lrow = l & 15, kg = l >> 4;
    int row0 = blockIdx.x * 64;      // 3125 blocks x 64 pairs = 200000 exact

    // stage Z = H[s] * H[d], split hi/lo, swizzled
    for (int i = 0; i < 4; ++i) {
        int idx = t + i * 512;       // 2048 float4 slots
        int r = idx >> 5;
        int c4 = (idx & 31) << 2;
        int p = row0 + r;
        int s  = (p < NP) ? ps[p] : ns[p - NP];
        int d2 = (p < NP) ? pd[p] : nd[p - NP];
        float4 a = *reinterpret_cast<const float4*>(H + (size_t)s * D + c4);
        float4 b = *reinterpret_cast<const float4*>(H + (size_t)d2 * D + c4);
        float z0 = a.x * b.x, z1 = a.y * b.y, z2 = a.z * b.z, z3 = a.w * b.w;
        ushort4 h4, l4;
        split2(z0, h4.x, l4.x); split2(z1, h4.y, l4.y);
        split2(z2, h4.z, l4.z); split2(z3, h4.w, l4.w);
        int db = r * 256 + ((c4 * 2) ^ ((r & 7) << 4));
        *reinterpret_cast<ushort4*>((char*)Zh + db) = h4;
        *reinterpret_cast<ushort4*>((char*)Zl + db) = l4;
    }

    f32x4 acc[4];
    for (int i = 0; i < 4; ++i) acc[i] = (f32x4)(0.f);

    for (int kc = 0; kc < 2; ++kc) {
        __syncthreads();             // covers Z writes (kc=0) and B reuse
        for (int i = 0; i < 2; ++i) {
            int s = t + i * 512;     // 1024 slots per array
            int n = s >> 3;
            int k8 = (s & 7) * 8;
            short8 vh = *reinterpret_cast<const short8*>(Wth + n * 128 + kc * 64 + k8);
            short8 vl = *reinterpret_cast<const short8*>(Wtl + n * 128 + kc * 64 + k8);
            int db = n * 128 + ((k8 * 2) ^ ((n & 7) << 4));
            *reinterpret_cast<short8*>((char*)Bh + db) = vh;
            *reinterpret_cast<short8*>((char*)Bl + db) = vl;
        }
        __syncthreads();

        for (int ks = 0; ks < 2; ++ks) {
            int zrow = rt * 16 + lrow;
            int kz2 = (kc * 64 + ks * 32 + kg * 8) * 2;
            int za = zrow * 256 + (kz2 ^ ((zrow & 7) << 4));
            short8 ah = *reinterpret_cast<const short8*>((char*)Zh + za);
            short8 al = *reinterpret_cast<const short8*>((char*)Zl + za);
            int kb2 = (ks * 32 + kg * 8) * 2;
            for (int ct = 0; ct < 4; ++ct) {
                int n = ch * 64 + ct * 16 + lrow;
                int db = n * 128 + (kb2 ^ ((n & 7) << 4));
                short8 bh = *reinterpret_cast<const short8*>((char*)Bh + db);
                short8 bl = *reinterpret_cast<const short8*>((char*)Bl + db);
                acc[ct] = __builtin_amdgcn_mfma_f32_16x16x32_bf16(ah, bh, acc[ct], 0, 0, 0);
                acc[ct] = __builtin_amdgcn_mfma_f32_16x16x32_bf16(ah, bl, acc[ct], 0, 0, 0);
                acc[ct] = __builtin_amdgcn_mfma_f32_16x16x32_bf16(al, bh, acc[ct], 0, 0, 0);
            }
        }
    }

    float partial[4] = {0.f, 0.f, 0.f, 0.f};
    for (int ct = 0; ct < 4; ++ct) {
        int n = ch * 64 + ct * 16 + lrow;
        float bv = bp1[n];
        float w2 = Wp2[n];
        for (int j = 0; j < 4; ++j) {
            float y = acc[ct][j] + bv;
            partial[j] += fmaxf(y, 0.f) * w2;
        }
    }
    for (int j = 0; j < 4; ++j)
        for (int off = 8; off >= 1; off >>= 1)
            partial[j] += __shfl_xor(partial[j], off);
    if (lrow == 0)
        for (int j = 0; j < 4; ++j)
            red[ch][rt * 16 + kg * 4 + j] = partial[j];
    __syncthreads();
    if (t < 64)
        out[row0 + t] = red[0][t] + red[1][t] + bp2[0];
}

// ---------------------------------------------------------------------------
extern "C" void kernel_launch(void* const* d_in, const int* in_sizes, int n_in,
                              void* d_out, int out_size, void* d_ws, size_t ws_size,
                              hipStream_t stream) {
    const float* x   = (const float*)d_in[0];
    const int*   es1 = (const int*)d_in[1];
    const int*   ed1 = (const int*)d_in[2];
    const int*   es2 = (const int*)d_in[3];
    const int*   ed2 = (const int*)d_in[4];
    const int*   ps  = (const int*)d_in[5];
    const int*   pd  = (const int*)d_in[6];
    const int*   ns  = (const int*)d_in[7];
    const int*   nd  = (const int*)d_in[8];
    const float* Ws1 = (const float*)d_in[9];
    const float* Wn1 = (const float*)d_in[10];
    const float* b1  = (const float*)d_in[11];
    const float* Ws2 = (const float*)d_in[12];
    const float* Wn2 = (const float*)d_in[13];
    const float* b2  = (const float*)d_in[14];
    const float* Wp1 = (const float*)d_in[15];
    const float* bp1 = (const float*)d_in[16];
    const float* Wp2 = (const float*)d_in[17];
    const float* bp2 = (const float*)d_in[18];
    float* out = (float*)d_out;

    char* ws = (char*)d_ws;
    size_t halfb = (size_t)NN * D * sizeof(ushort_t);  // 25.6 MB
    ushort_t* x_h    = (ushort_t*)(ws);                // -> h_h after layer-1 GEMM
    ushort_t* x_l    = (ushort_t*)(ws + halfb);        // -> h_l
    ushort_t* mean_h = (ushort_t*)(ws + 2 * halfb);
    ushort_t* mean_l = (ushort_t*)(ws + 3 * halfb);
    float*    hf     = (float*)(ws + 4 * halfb);       // fp32 h; later fp32 h2
    char* wsp = ws + 4 * halfb + (size_t)NN * D * sizeof(float);
    ushort_t* w1t_h  = (ushort_t*)wsp;
    ushort_t* w1t_l  = w1t_h + 256 * 128;
    ushort_t* w2t_h  = w1t_l + 256 * 128;
    ushort_t* w2t_l  = w2t_h + 256 * 128;
    ushort_t* wpt_h  = w2t_l + 256 * 128;
    ushort_t* wpt_l  = wpt_h + 128 * 128;
    int* cnt     = (int*)(wpt_l + 128 * 128 + 64);     // 2*NN
    int* row_off = cnt + 2 * NN;                        // 2*NN + 1
    int* cursor  = row_off + 2 * NN + 1;                // 2*NN
    int* csr     = cursor + 2 * NN;                     // 2*NE
    int* bsums   = csr + 2 * NE;                        // NB2

    dim3 blk(256), blk512(512);
    int e2Blocks     = (2 * NE + 255) / 256;     // 7813
    int gatherBlocks = NN * 32 / 256;            // 12500 exact
    int gemmBlocks   = (NN + 127) / 128;         // 782
    int predBlocks   = 2 * NP / 64;              // 3125 exact

    // ---- Prep + CSR build (both layers) ----
    hipMemsetAsync(cnt, 0, 2 * NN * sizeof(int), stream);
    prep_kernel<<<12820, blk, 0, stream>>>(
        x, Ws1, Wn1, Ws2, Wn2, Wp1,
        x_h, x_l, w1t_h, w1t_l, w2t_h, w2t_l, wpt_h, wpt_l);
    count2_kernel<<<e2Blocks, blk, 0, stream>>>(ed1, ed2, cnt);
    block_sum_kernel<<<NB2, blk, 0, stream>>>(cnt, bsums);
    scan_sums_kernel<<<1, 1024, 0, stream>>>(bsums);
    block_scan_kernel<<<NB2, blk, 0, stream>>>(cnt, bsums, row_off, cursor);
    fill2_kernel<<<e2Blocks, blk, 0, stream>>>(es1, ed1, es2, ed2, cursor, csr);

    // ---- Layer 1 ----
    gather_mean_kernel<<<gatherBlocks, blk, 0, stream>>>(x, row_off, csr, mean_h, mean_l);
    // h hi/lo overwrites x_h/x_l (waves only read their own rows) + fp32 h to hf
    mfma_sage_gemm<true, true, true><<<gemmBlocks, blk512, 0, stream>>>(
        x_h, x_l, mean_h, mean_l, w1t_h, w1t_l, b1, x_h, x_l, hf);

    // ---- Layer 2 ----
    gather_mean_kernel<<<gatherBlocks, blk, 0, stream>>>(hf, row_off + NN, csr, mean_h, mean_l);
    // h2 fp32 overwrites hf (dead after gather above)
    mfma_sage_gemm<false, false, true><<<gemmBlocks, blk512, 0, stream>>>(
        x_h, x_l, mean_h, mean_l, w2t_h, w2t_l, b2, nullptr, nullptr, hf);

    // ---- Predictor (pos+neg merged) ----
    mfma_predictor<<<predBlocks, blk512, 0, stream>>>(
        hf, ps, pd, ns, nd, wpt_h, wpt_l, bp1, Wp2, bp2, out);
}

// Round 7
// 366.369 us; speedup vs baseline: 10.6200x; 1.5060x over previous
//
#include <hip/hip_runtime.h>

typedef unsigned short ushort_t;
typedef __attribute__((ext_vector_type(8))) short short8;
typedef __attribute__((ext_vector_type(4))) float f32x4;

// Problem constants
constexpr int NN = 100000;   // nodes
constexpr int D  = 128;      // feature dim
constexpr int NE = 1000000;  // edges per layer
constexpr int NP = 100000;   // pos/neg pairs

// Bucketed CSR build
constexpr int BK_SHIFT = 9;                      // 512 nodes per bucket
constexpr int NBK_L = (NN + 511) >> BK_SHIFT;    // 196 buckets per layer
constexpr int NBK   = 2 * NBK_L;                 // 392 total
constexpr int ACHUNK = 4096;                     // edges per block in A passes
constexpr int ABLOCKS = (2 * NE + ACHUNK - 1) / ACHUNK;   // 489

// ---------------- bf16 helpers (manual RNE) --------------------------------
__device__ __forceinline__ float bf2f(ushort_t u) {
    union { unsigned int i; float f; } v; v.i = ((unsigned int)u) << 16; return v.f;
}
__device__ __forceinline__ ushort_t f2bf(float x) {
    union { float f; unsigned int i; } v; v.f = x;
    unsigned int r = v.i + 0x7fffu + ((v.i >> 16) & 1u);
    return (ushort_t)(r >> 16);
}
__device__ __forceinline__ void split2(float x, ushort_t& h, ushort_t& l) {
    h = f2bf(x);
    l = f2bf(x - bf2f(h));
}

// ---------------------------------------------------------------------------
// Fused prep: convert x -> hi/lo bf16; transpose+split all weights.
// ---------------------------------------------------------------------------
__global__ void __launch_bounds__(256) prep_kernel(
    const float* __restrict__ x,
    const float* __restrict__ Ws1, const float* __restrict__ Wn1,
    const float* __restrict__ Ws2, const float* __restrict__ Wn2,
    const float* __restrict__ Wp1,
    ushort_t* __restrict__ xh, ushort_t* __restrict__ xl,
    ushort_t* __restrict__ w1h, ushort_t* __restrict__ w1l,
    ushort_t* __restrict__ w2h, ushort_t* __restrict__ w2l,
    ushort_t* __restrict__ wph, ushort_t* __restrict__ wpl)
{
    int b = blockIdx.x;
    if (b < 12500) {
        int tid = b * 256 + threadIdx.x;
        float4 v = *reinterpret_cast<const float4*>(x + (size_t)tid * 4);
        ushort4 h4, l4;
        split2(v.x, h4.x, l4.x); split2(v.y, h4.y, l4.y);
        split2(v.z, h4.z, l4.z); split2(v.w, h4.w, l4.w);
        *reinterpret_cast<ushort4*>(xh + (size_t)tid * 4) = h4;
        *reinterpret_cast<ushort4*>(xl + (size_t)tid * 4) = l4;
    } else if (b < 12756) {
        int layer2 = (b >= 12628);
        int tid = (b - (layer2 ? 12628 : 12500)) * 256 + threadIdx.x;  // 32768
        int k = tid >> 7, n = tid & 127;
        const float* Ws = layer2 ? Ws2 : Ws1;
        const float* Wn = layer2 ? Wn2 : Wn1;
        ushort_t* Wth = layer2 ? w2h : w1h;
        ushort_t* Wtl = layer2 ? w2l : w1l;
        float v = (k < 128) ? Ws[k * 128 + n] : Wn[(k - 128) * 128 + n];
        ushort_t h, l; split2(v, h, l);
        Wth[n * 256 + k] = h; Wtl[n * 256 + k] = l;
    } else {
        int tid = (b - 12756) * 256 + threadIdx.x;   // 16384
        int k = tid >> 7, n = tid & 127;
        float v = Wp1[k * 128 + n];
        ushort_t h, l; split2(v, h, l);
        wph[n * 128 + k] = h; wpl[n * 128 + k] = l;
    }
}

// ---------------------------------------------------------------------------
// Bucketed CSR build, pass A1: per-block LDS histogram -> global bucket totals
// ---------------------------------------------------------------------------
__global__ void __launch_bounds__(256) bucket_count_kernel(
    const int* __restrict__ ed1, const int* __restrict__ ed2,
    int* __restrict__ btot)
{
    __shared__ int hist[NBK];
    int t = threadIdx.x;
    for (int i = t; i < NBK; i += 256) hist[i] = 0;
    __syncthreads();
    int base = blockIdx.x * ACHUNK;
    for (int it = 0; it < ACHUNK / 256; ++it) {
        int e = base + it * 256 + t;
        if (e < 2 * NE) {
            int layer2 = (e >= NE);
            int d = layer2 ? ed2[e - NE] : ed1[e];
            atomicAdd(&hist[(layer2 ? NBK_L : 0) + (d >> BK_SHIFT)], 1);
        }
    }
    __syncthreads();
    for (int i = t; i < NBK; i += 256)
        if (hist[i]) atomicAdd(&btot[i], hist[i]);
}

// ---------------------------------------------------------------------------
// Bucket scan: exclusive scan of 392 totals -> bbase[393], bcur[392]
// ---------------------------------------------------------------------------
__global__ void __launch_bounds__(512) bucket_scan_kernel(
    const int* __restrict__ btot, int* __restrict__ bbase, int* __restrict__ bcur)
{
    __shared__ int s[512];
    int t = threadIdx.x;
    int v = (t < NBK) ? btot[t] : 0;
    s[t] = v;
    __syncthreads();
    for (int off = 1; off < 512; off <<= 1) {
        int u = (t >= off) ? s[t - off] : 0;
        __syncthreads();
        s[t] += u;
        __syncthreads();
    }
    if (t < NBK) {
        int ex = s[t] - v;
        bbase[t] = ex;
        bcur[t] = ex;
        if (t == NBK - 1) bbase[NBK] = s[t];   // == 2*NE
    }
}

// ---------------------------------------------------------------------------
// Pass A2: scatter (src,dst) pairs into bucket-segmented pairbuf.
// Per-block ranges reserved with one global atomic per (block,bucket).
// ---------------------------------------------------------------------------
__global__ void __launch_bounds__(256) bucket_scatter_kernel(
    const int* __restrict__ es1, const int* __restrict__ ed1,
    const int* __restrict__ es2, const int* __restrict__ ed2,
    int* __restrict__ bcur, int2* __restrict__ pair)
{
    __shared__ int hist[NBK];
    __shared__ int rbase[NBK];
    __shared__ int cur[NBK];
    int t = threadIdx.x;
    for (int i = t; i < NBK; i += 256) hist[i] = 0;
    __syncthreads();
    int base = blockIdx.x * ACHUNK;
    for (int it = 0; it < ACHUNK / 256; ++it) {
        int e = base + it * 256 + t;
        if (e < 2 * NE) {
            int layer2 = (e >= NE);
            int d = layer2 ? ed2[e - NE] : ed1[e];
            atomicAdd(&hist[(layer2 ? NBK_L : 0) + (d >> BK_SHIFT)], 1);
        }
    }
    __syncthreads();
    for (int i = t; i < NBK; i += 256) {
        int h = hist[i];
        rbase[i] = h ? atomicAdd(&bcur[i], h) : 0;
        cur[i] = 0;
    }
    __syncthreads();
    for (int it = 0; it < ACHUNK / 256; ++it) {
        int e = base + it * 256 + t;
        if (e < 2 * NE) {
            int layer2 = (e >= NE);
            int s = layer2 ? es2[e - NE] : es1[e];
            int d = layer2 ? ed2[e - NE] : ed1[e];
            int bkt = (layer2 ? NBK_L : 0) + (d >> BK_SHIFT);
            int r = atomicAdd(&cur[bkt], 1);
            pair[(size_t)rbase[bkt] + r] = make_int2(s, d);
        }
    }
}

// ---------------------------------------------------------------------------
// Pass B: one block per bucket. LDS per-node counts -> LDS scan -> row_off,
// then LDS-cursor scatter of src into the bucket's csr window (L2-local).
// ---------------------------------------------------------------------------
__global__ void __launch_bounds__(256) bucket_build_kernel(
    const int2* __restrict__ pair, const int* __restrict__ bbase,
    int* __restrict__ row_off, int* __restrict__ csr)
{
    __shared__ int cnt[512];
    __shared__ int sc[256];
    int b = blockIdx.x;
    int t = threadIdx.x;
    int layer2 = (b >= NBK_L);
    int n0 = (b - (layer2 ? NBK_L : 0)) << BK_SHIFT;
    int nodes = min(512, NN - n0);
    int gnode0 = n0 + (layer2 ? NN : 0);
    int e0 = bbase[b], e1 = bbase[b + 1];
    int m = e1 - e0;

    cnt[t] = 0; cnt[t + 256] = 0;
    __syncthreads();
    for (int j = t; j < m; j += 256)
        atomicAdd(&cnt[pair[(size_t)e0 + j].y - n0], 1);
    __syncthreads();

    // exclusive scan of cnt[512] using 256 threads (pairs)
    int a0 = cnt[2 * t], a1 = cnt[2 * t + 1];
    sc[t] = a0 + a1;
    __syncthreads();
    for (int off = 1; off < 256; off <<= 1) {
        int u = (t >= off) ? sc[t - off] : 0;
        __syncthreads();
        sc[t] += u;
        __syncthreads();
    }
    int ex = sc[t] - (a0 + a1);
    cnt[2 * t] = ex;
    cnt[2 * t + 1] = ex + a0;
    __syncthreads();

    // write row_off for this bucket's nodes
    for (int i = t; i < nodes; i += 256)
        row_off[gnode0 + i] = e0 + cnt[i];
    if (b == NBK - 1 && t == 0) row_off[2 * NN] = 2 * NE;
    __syncthreads();

    // scatter src into csr via LDS cursors
    for (int j = t; j < m; j += 256) {
        int2 p = pair[(size_t)e0 + j];
        int r = atomicAdd(&cnt[p.y - n0], 1);
        csr[(size_t)e0 + r] = p.x;
    }
}

// ---------------------------------------------------------------------------
// Gather-mean from FP32 features, 8x unrolled. Emits hi/lo bf16 mean.
// ---------------------------------------------------------------------------
__global__ void __launch_bounds__(256) gather_mean_kernel(
    const float* __restrict__ feat,
    const int* __restrict__ row_off,
    const int* __restrict__ csr,
    ushort_t* __restrict__ mh, ushort_t* __restrict__ ml)
{
    int tid = blockIdx.x * 256 + threadIdx.x;
    int g = tid >> 5;
    int lane = tid & 31;
    int c = lane << 2;
    int beg = row_off[g], end = row_off[g + 1];
    float ax0 = 0.f, ay0 = 0.f, az0 = 0.f, aw0 = 0.f;
    float ax1 = 0.f, ay1 = 0.f, az1 = 0.f, aw1 = 0.f;
    int j = beg;
    for (; j + 8 <= end; j += 8) {
        int s0 = csr[j + 0], s1 = csr[j + 1], s2 = csr[j + 2], s3 = csr[j + 3];
        int s4 = csr[j + 4], s5 = csr[j + 5], s6 = csr[j + 6], s7 = csr[j + 7];
        float4 v0 = *reinterpret_cast<const float4*>(feat + (size_t)s0 * D + c);
        float4 v1 = *reinterpret_cast<const float4*>(feat + (size_t)s1 * D + c);
        float4 v2 = *reinterpret_cast<const float4*>(feat + (size_t)s2 * D + c);
        float4 v3 = *reinterpret_cast<const float4*>(feat + (size_t)s3 * D + c);
        float4 v4 = *reinterpret_cast<const float4*>(feat + (size_t)s4 * D + c);
        float4 v5 = *reinterpret_cast<const float4*>(feat + (size_t)s5 * D + c);
        float4 v6 = *reinterpret_cast<const float4*>(feat + (size_t)s6 * D + c);
        float4 v7 = *reinterpret_cast<const float4*>(feat + (size_t)s7 * D + c);
        ax0 += v0.x + v1.x + v4.x + v5.x; ay0 += v0.y + v1.y + v4.y + v5.y;
        az0 += v0.z + v1.z + v4.z + v5.z; aw0 += v0.w + v1.w + v4.w + v5.w;
        ax1 += v2.x + v3.x + v6.x + v7.x; ay1 += v2.y + v3.y + v6.y + v7.y;
        az1 += v2.z + v3.z + v6.z + v7.z; aw1 += v2.w + v3.w + v6.w + v7.w;
    }
    for (; j < end; ++j) {
        int s = csr[j];
        float4 v = *reinterpret_cast<const float4*>(feat + (size_t)s * D + c);
        ax0 += v.x; ay0 += v.y; az0 += v.z; aw0 += v.w;
    }
    float rd = 1.0f / fmaxf((float)(end - beg), 1.0f);
    float mx = (ax0 + ax1) * rd, my = (ay0 + ay1) * rd;
    float mz = (az0 + az1) * rd, mw = (aw0 + aw1) * rd;
    ushort4 h4, l4;
    split2(mx, h4.x, l4.x); split2(my, h4.y, l4.y);
    split2(mz, h4.z, l4.z); split2(mw, h4.w, l4.w);
    *reinterpret_cast<ushort4*>(mh + (size_t)g * D + c) = h4;
    *reinterpret_cast<ushort4*>(ml + (size_t)g * D + c) = l4;
}

// ---------------------------------------------------------------------------
// MFMA split-bf16 SAGEConv GEMM, 128 rows/block, 8 waves.
// ---------------------------------------------------------------------------
template<bool RELU, bool WSPLIT, bool WF32>
__global__ void __launch_bounds__(512) mfma_sage_gemm(
    const ushort_t* __restrict__ Ah_self, const ushort_t* __restrict__ Al_self,
    const ushort_t* __restrict__ Ah_nei,  const ushort_t* __restrict__ Al_nei,
    const ushort_t* __restrict__ Wth, const ushort_t* __restrict__ Wtl,
    const float* __restrict__ bias,
    ushort_t* __restrict__ out_h, ushort_t* __restrict__ out_l,
    float* __restrict__ out_f)
{
    __shared__ short Bh[128 * 64];   // [n][64k] bf16, swizzled
    __shared__ short Bl[128 * 64];

    int t = threadIdx.x;
    int l = t & 63, w = t >> 6;      // 8 waves; wave = row-tile
    int lrow = l & 15, kg = l >> 4;
    int row0 = blockIdx.x * 128;
    int arow = row0 + w * 16 + lrow;
    int arow_c = min(arow, NN - 1);  // clamp for tail block loads

    f32x4 acc[8];
    for (int i = 0; i < 8; ++i) acc[i] = (f32x4)(0.f);

    for (int half = 0; half < 2; ++half) {
        const ushort_t* Ah = half ? Ah_nei : Ah_self;
        const ushort_t* Al = half ? Al_nei : Al_self;
        for (int kc2 = 0; kc2 < 2; ++kc2) {
            int kcat = half * 128 + kc2 * 64;
            __syncthreads();
            for (int i = 0; i < 2; ++i) {
                int s = t + i * 512;            // 1024 b128 slots per array
                int n = s >> 3;
                int k8 = (s & 7) * 8;
                short8 vh = *reinterpret_cast<const short8*>(Wth + n * 256 + kcat + k8);
                short8 vl = *reinterpret_cast<const short8*>(Wtl + n * 256 + kcat + k8);
                int db = n * 128 + ((k8 * 2) ^ ((n & 7) << 4));
                *reinterpret_cast<short8*>((char*)Bh + db) = vh;
                *reinterpret_cast<short8*>((char*)Bl + db) = vl;
            }
            __syncthreads();

            for (int ks = 0; ks < 2; ++ks) {
                int ka = kc2 * 64 + ks * 32 + kg * 8;
                short8 ah = *reinterpret_cast<const short8*>(Ah + (size_t)arow_c * D + ka);
                short8 al = *reinterpret_cast<const short8*>(Al + (size_t)arow_c * D + ka);
                int kb2 = (ks * 32 + kg * 8) * 2;
                for (int ct = 0; ct < 8; ++ct) {
                    int n = ct * 16 + lrow;
                    int db = n * 128 + (kb2 ^ ((n & 7) << 4));
                    short8 bh = *reinterpret_cast<const short8*>((char*)Bh + db);
                    short8 bl = *reinterpret_cast<const short8*>((char*)Bl + db);
                    acc[ct] = __builtin_amdgcn_mfma_f32_16x16x32_bf16(ah, bh, acc[ct], 0, 0, 0);
                    acc[ct] = __builtin_amdgcn_mfma_f32_16x16x32_bf16(ah, bl, acc[ct], 0, 0, 0);
                    acc[ct] = __builtin_amdgcn_mfma_f32_16x16x32_bf16(al, bh, acc[ct], 0, 0, 0);
                }
            }
        }
    }

    // epilogue: C/D layout col = lane&15, row = (lane>>4)*4 + j
    for (int ct = 0; ct < 8; ++ct) {
        int n = ct * 16 + lrow;
        float bv = bias[n];
        for (int j = 0; j < 4; ++j) {
            int r = row0 + w * 16 + kg * 4 + j;
            if (r >= NN) continue;
            float y = acc[ct][j] + bv;
            if (RELU) y = fmaxf(y, 0.f);
            if (WF32) out_f[(size_t)r * D + n] = y;
            if (WSPLIT) {
                ushort_t hh, ll; split2(y, hh, ll);
                out_h[(size_t)r * D + n] = hh;
                out_l[(size_t)r * D + n] = ll;
            }
        }
    }
}

// ---------------------------------------------------------------------------
// MFMA predictor, merged pos+neg: 64 pairs/block, 8 waves.
// ---------------------------------------------------------------------------
__global__ void __launch_bounds__(512) mfma_predictor(
    const float* __restrict__ H,
    const int* __restrict__ ps, const int* __restrict__ pd,
    const int* __restrict__ ns, const int* __restrict__ nd,
    const ushort_t* __restrict__ Wth, const ushort_t* __restrict__ Wtl,
    const float* __restrict__ bp1,
    const float* __restrict__ Wp2, const float* __restrict__ bp2,
    float* __restrict__ out)
{
    __shared__ short Zh[64 * 128];
    __shared__ short Zl[64 * 128];
    __shared__ short Bh[128 * 64];
    __shared__ short Bl[128 * 64];
    __shared__ float red[2][64];

    int t = threadIdx.x;
    int l = t & 63, w = t >> 6;
    int rt = w >> 1, ch = w & 1;
    int lrow = l & 15, kg = l >> 4;
    int row0 = blockIdx.x * 64;      // 3125 blocks x 64 pairs = 200000 exact

    for (int i = 0; i < 4; ++i) {
        int idx = t + i * 512;       // 2048 float4 slots
        int r = idx >> 5;
        int c4 = (idx & 31) << 2;
        int p = row0 + r;
        int s  = (p < NP) ? ps[p] : ns[p - NP];
        int d2 = (p < NP) ? pd[p] : nd[p - NP];
        float4 a = *reinterpret_cast<const float4*>(H + (size_t)s * D + c4);
        float4 b = *reinterpret_cast<const float4*>(H + (size_t)d2 * D + c4);
        float z0 = a.x * b.x, z1 = a.y * b.y, z2 = a.z * b.z, z3 = a.w * b.w;
        ushort4 h4, l4;
        split2(z0, h4.x, l4.x); split2(z1, h4.y, l4.y);
        split2(z2, h4.z, l4.z); split2(z3, h4.w, l4.w);
        int db = r * 256 + ((c4 * 2) ^ ((r & 7) << 4));
        *reinterpret_cast<ushort4*>((char*)Zh + db) = h4;
        *reinterpret_cast<ushort4*>((char*)Zl + db) = l4;
    }

    f32x4 acc[4];
    for (int i = 0; i < 4; ++i) acc[i] = (f32x4)(0.f);

    for (int kc = 0; kc < 2; ++kc) {
        __syncthreads();
        for (int i = 0; i < 2; ++i) {
            int s = t + i * 512;
            int n = s >> 3;
            int k8 = (s & 7) * 8;
            short8 vh = *reinterpret_cast<const short8*>(Wth + n * 128 + kc * 64 + k8);
            short8 vl = *reinterpret_cast<const short8*>(Wtl + n * 128 + kc * 64 + k8);
            int db = n * 128 + ((k8 * 2) ^ ((n & 7) << 4));
            *reinterpret_cast<short8*>((char*)Bh + db) = vh;
            *reinterpret_cast<short8*>((char*)Bl + db) = vl;
        }
        __syncthreads();

        for (int ks = 0; ks < 2; ++ks) {
            int zrow = rt * 16 + lrow;
            int kz2 = (kc * 64 + ks * 32 + kg * 8) * 2;
            int za = zrow * 256 + (kz2 ^ ((zrow & 7) << 4));
            short8 ah = *reinterpret_cast<const short8*>((char*)Zh + za);
            short8 al = *reinterpret_cast<const short8*>((char*)Zl + za);
            int kb2 = (ks * 32 + kg * 8) * 2;
            for (int ct = 0; ct < 4; ++ct) {
                int n = ch * 64 + ct * 16 + lrow;
                int db = n * 128 + (kb2 ^ ((n & 7) << 4));
                short8 bh = *reinterpret_cast<const short8*>((char*)Bh + db);
                short8 bl = *reinterpret_cast<const short8*>((char*)Bl + db);
                acc[ct] = __builtin_amdgcn_mfma_f32_16x16x32_bf16(ah, bh, acc[ct], 0, 0, 0);
                acc[ct] = __builtin_amdgcn_mfma_f32_16x16x32_bf16(ah, bl, acc[ct], 0, 0, 0);
                acc[ct] = __builtin_amdgcn_mfma_f32_16x16x32_bf16(al, bh, acc[ct], 0, 0, 0);
            }
        }
    }

    float partial[4] = {0.f, 0.f, 0.f, 0.f};
    for (int ct = 0; ct < 4; ++ct) {
        int n = ch * 64 + ct * 16 + lrow;
        float bv = bp1[n];
        float w2 = Wp2[n];
        for (int j = 0; j < 4; ++j) {
            float y = acc[ct][j] + bv;
            partial[j] += fmaxf(y, 0.f) * w2;
        }
    }
    for (int j = 0; j < 4; ++j)
        for (int off = 8; off >= 1; off >>= 1)
            partial[j] += __shfl_xor(partial[j], off);
    if (lrow == 0)
        for (int j = 0; j < 4; ++j)
            red[ch][rt * 16 + kg * 4 + j] = partial[j];
    __syncthreads();
    if (t < 64)
        out[row0 + t] = red[0][t] + red[1][t] + bp2[0];
}

// ---------------------------------------------------------------------------
extern "C" void kernel_launch(void* const* d_in, const int* in_sizes, int n_in,
                              void* d_out, int out_size, void* d_ws, size_t ws_size,
                              hipStream_t stream) {
    const float* x   = (const float*)d_in[0];
    const int*   es1 = (const int*)d_in[1];
    const int*   ed1 = (const int*)d_in[2];
    const int*   es2 = (const int*)d_in[3];
    const int*   ed2 = (const int*)d_in[4];
    const int*   ps  = (const int*)d_in[5];
    const int*   pd  = (const int*)d_in[6];
    const int*   ns  = (const int*)d_in[7];
    const int*   nd  = (const int*)d_in[8];
    const float* Ws1 = (const float*)d_in[9];
    const float* Wn1 = (const float*)d_in[10];
    const float* b1  = (const float*)d_in[11];
    const float* Ws2 = (const float*)d_in[12];
    const float* Wn2 = (const float*)d_in[13];
    const float* b2  = (const float*)d_in[14];
    const float* Wp1 = (const float*)d_in[15];
    const float* bp1 = (const float*)d_in[16];
    const float* Wp2 = (const float*)d_in[17];
    const float* bp2 = (const float*)d_in[18];
    float* out = (float*)d_out;

    char* ws = (char*)d_ws;
    size_t halfb = (size_t)NN * D * sizeof(ushort_t);  // 25.6 MB
    ushort_t* x_h    = (ushort_t*)(ws);                // -> h_h after layer-1 GEMM
    ushort_t* x_l    = (ushort_t*)(ws + halfb);        // -> h_l
    ushort_t* mean_h = (ushort_t*)(ws + 2 * halfb);
    ushort_t* mean_l = (ushort_t*)(ws + 3 * halfb);
    float*    hf     = (float*)(ws + 4 * halfb);       // fp32 h; later fp32 h2
    int2*     pair   = (int2*)hf;                      // pairbuf overlays hf
                                                       // (dead before gemm1)
    char* wsp = ws + 4 * halfb + (size_t)NN * D * sizeof(float);
    ushort_t* w1t_h  = (ushort_t*)wsp;
    ushort_t* w1t_l  = w1t_h + 256 * 128;
    ushort_t* w2t_h  = w1t_l + 256 * 128;
    ushort_t* w2t_l  = w2t_h + 256 * 128;
    ushort_t* wpt_h  = w2t_l + 256 * 128;
    ushort_t* wpt_l  = wpt_h + 128 * 128;
    int* row_off = (int*)(wpt_l + 128 * 128 + 64);     // 2*NN + 1
    int* csr     = row_off + 2 * NN + 2;               // 2*NE
    int* btot    = csr + 2 * NE;                       // NBK
    int* bbase   = btot + NBK;                         // NBK + 1
    int* bcur    = bbase + NBK + 1;                    // NBK

    dim3 blk(256), blk512(512);
    int gatherBlocks = NN * 32 / 256;            // 12500 exact
    int gemmBlocks   = (NN + 127) / 128;         // 782
    int predBlocks   = 2 * NP / 64;              // 3125 exact

    // ---- Prep + bucketed CSR build (both layers) ----
    hipMemsetAsync(btot, 0, NBK * sizeof(int), stream);
    prep_kernel<<<12820, blk, 0, stream>>>(
        x, Ws1, Wn1, Ws2, Wn2, Wp1,
        x_h, x_l, w1t_h, w1t_l, w2t_h, w2t_l, wpt_h, wpt_l);
    bucket_count_kernel<<<ABLOCKS, blk, 0, stream>>>(ed1, ed2, btot);
    bucket_scan_kernel<<<1, 512, 0, stream>>>(btot, bbase, bcur);
    bucket_scatter_kernel<<<ABLOCKS, blk, 0, stream>>>(es1, ed1, es2, ed2, bcur, pair);
    bucket_build_kernel<<<NBK, blk, 0, stream>>>(pair, bbase, row_off, csr);

    // ---- Layer 1 ----
    gather_mean_kernel<<<gatherBlocks, blk, 0, stream>>>(x, row_off, csr, mean_h, mean_l);
    // h hi/lo overwrites x_h/x_l (waves only read their own rows) + fp32 h to hf
    // (pairbuf is dead from here on)
    mfma_sage_gemm<true, true, true><<<gemmBlocks, blk512, 0, stream>>>(
        x_h, x_l, mean_h, mean_l, w1t_h, w1t_l, b1, x_h, x_l, hf);

    // ---- Layer 2 ----
    gather_mean_kernel<<<gatherBlocks, blk, 0, stream>>>(hf, row_off + NN, csr, mean_h, mean_l);
    // h2 fp32 overwrites hf (dead after gather above)
    mfma_sage_gemm<false, false, true><<<gemmBlocks, blk512, 0, stream>>>(
        x_h, x_l, mean_h, mean_l, w2t_h, w2t_l, b2, nullptr, nullptr, hf);

    // ---- Predictor (pos+neg merged) ----
    mfma_predictor<<<predBlocks, blk512, 0, stream>>>(
        hf, ps, pd, ns, nd, wpt_h, wpt_l, bp1, Wp2, bp2, out);
}